// Round 1
// baseline (54826.196 us; speedup 1.0000x reference)
//
#include <hip/hip_runtime.h>
#include <cmath>
#include <cstdint>
#include <cstddef>

// Problem dims (fixed by the reference)
#define BB   128   // batch
#define TT   512   // encoder sequence length
#define INF  64    // encoder input features
#define HH   1024  // hidden size
#define NG   4096  // 4*HH, gates i,f,g,o (PyTorch order)
#define SS   64    // decoder steps

typedef __attribute__((ext_vector_type(8))) short sh8;
typedef __attribute__((ext_vector_type(4))) float f32x4;

// bf16 <-> f32 helpers on raw ushort bits (RNE; inputs are small/finite)
__device__ __forceinline__ float bf2f(unsigned short u) {
  unsigned int i = ((unsigned int)u) << 16;
  return __builtin_bit_cast(float, i);
}
__device__ __forceinline__ unsigned short f2bf(float f) {
  unsigned int u = __builtin_bit_cast(unsigned int, f);
  u += 0x7FFFu + ((u >> 16) & 1u);
  return (unsigned short)(u >> 16);
}

#if defined(__HIP_DEVICE_COMPILE__)
// MFMA shim: gfx950's __builtin_amdgcn_mfma_f32_16x16x32_bf16 takes either a
// short8 or a __bf16x8 operand depending on compiler version; detect via SFINAE.
typedef __attribute__((ext_vector_type(8))) __bf16 bf8;
template <class T> T&& my_declval();
template <class V, class = void> struct mfma_takes { static constexpr bool value = false; };
template <class V>
struct mfma_takes<V, decltype((void)__builtin_amdgcn_mfma_f32_16x16x32_bf16(
                        my_declval<V>(), my_declval<V>(), my_declval<f32x4>(), 0, 0, 0))> {
  static constexpr bool value = true;
};
template <class V>
__device__ __forceinline__ f32x4 mfma_imp(V a, V b, f32x4 c) {
  return __builtin_amdgcn_mfma_f32_16x16x32_bf16(a, b, c, 0, 0, 0);
}
template <int D = 0>
__device__ __forceinline__ f32x4 mfma_bf16(sh8 a, sh8 b, f32x4 c) {
  if constexpr (mfma_takes<sh8>::value) {
    return mfma_imp<sh8>(a, b, c);
  } else {
    return mfma_imp<bf8>(__builtin_bit_cast(bf8, a), __builtin_bit_cast(bf8, b), c);
  }
}
#endif

// ---- weight preprocessing: fp32 [NG][K] row-major -> split bf16 hi/lo in
// MFMA-B-fragment order. For (n,k):
//   elem index = (((n>>4)*(K/32) + (k>>5))*64 + ((k>>3)&3)*16 + (n&15))*8 + (k&7)
// so a wave's 64 lanes load 16B each, fully coalesced, for tile (n>>4, k>>5).
__global__ __launch_bounds__(256) void prep_weight(const float* __restrict__ W,
                                                   unsigned short* __restrict__ hi,
                                                   unsigned short* __restrict__ lo,
                                                   int lk) {
  const int K = 1 << lk;
  const int idx = blockIdx.x * 256 + threadIdx.x;
  if (idx >= (NG << lk)) return;
  const int n = idx >> lk;
  const int k = idx & (K - 1);
  const float v = W[idx];
  const unsigned short h = f2bf(v);
  const unsigned short l = f2bf(v - bf2f(h));
  const int nkch = K >> 5;
  const size_t o =
      ((((size_t)(n >> 4) * nkch + (k >> 5)) * 64) + (((k >> 3) & 3) * 16) + (n & 15)) * 8 +
      (k & 7);
  hi[o] = h;
  lo[o] = l;
}

__global__ __launch_bounds__(256) void prep_bias(const float* __restrict__ a,
                                                 const float* __restrict__ b,
                                                 float* __restrict__ o) {
  const int i = blockIdx.x * 256 + threadIdx.x;
  if (i < NG) o[i] = a[i] + b[i];
}

// ---- one LSTM cell step.
// grid (64 j-tiles, 2 m-groups), block 256 = 4 waves; wave -> m-tile (16 batch
// rows), owns the 4 gate N-tiles of its j-tile. Split-bf16: acc += aH*bH +
// aH*bL + aL*bH (fp32 accumulate), error ~2^-15 relative.
// MODE 0: fp32 x input (K=INF);  MODE 1: bf16 hi/lo input (K=HH);  MODE 2: rank-1 scalar input.
template <int MODE>
__global__ __launch_bounds__(256) void lstm_step(
    const float* __restrict__ xin, int xstride,
    const unsigned short* __restrict__ ain_h, const unsigned short* __restrict__ ain_l,
    const float* __restrict__ inp,
    const unsigned short* __restrict__ win_h, const unsigned short* __restrict__ win_l,
    const float* __restrict__ w0col,
    const unsigned short* __restrict__ whh_h, const unsigned short* __restrict__ whh_l,
    const float* __restrict__ bias,
    const unsigned short* __restrict__ h_h, const unsigned short* __restrict__ h_l,
    unsigned short* __restrict__ nh_h, unsigned short* __restrict__ nh_l,
    float* __restrict__ cst) {
#if defined(__HIP_DEVICE_COMPILE__)
  const int lane = threadIdx.x & 63;
  const int wid  = threadIdx.x >> 6;
  const int jt   = blockIdx.x;            // 0..63
  const int mt   = blockIdx.y * 4 + wid;  // 0..7
  const int col  = lane & 15;
  const int kg   = lane >> 4;
  const int arow = mt * 16 + col;  // batch row whose A-fragment this lane loads

  f32x4 acc[4];
#pragma unroll
  for (int g = 0; g < 4; ++g) acc[g] = f32x4{0.f, 0.f, 0.f, 0.f};

  if constexpr (MODE == 0) {
    const float* xr = xin + (size_t)arow * xstride;
#pragma unroll
    for (int kc = 0; kc < INF / 32; ++kc) {
      const int kb = kc * 32 + kg * 8;
      sh8 aH, aL;
#pragma unroll
      for (int e = 0; e < 8; ++e) {
        const float v = xr[kb + e];
        const unsigned short hb = f2bf(v);
        const unsigned short lb = f2bf(v - bf2f(hb));
        aH[e] = (short)hb;
        aL[e] = (short)lb;
      }
#pragma unroll
      for (int g = 0; g < 4; ++g) {
        const size_t bo = ((((size_t)(g * 64 + jt)) * (INF / 32) + kc) * 64 + lane) * 8;
        const sh8 bH = *(const sh8*)(win_h + bo);
        const sh8 bL = *(const sh8*)(win_l + bo);
        acc[g] = mfma_bf16(aH, bH, acc[g]);
        acc[g] = mfma_bf16(aH, bL, acc[g]);
        acc[g] = mfma_bf16(aL, bH, acc[g]);
      }
    }
  } else if constexpr (MODE == 1) {
    const unsigned short* arh = ain_h + (size_t)arow * HH;
    const unsigned short* arl = ain_l + (size_t)arow * HH;
    for (int kc = 0; kc < HH / 32; ++kc) {
      const int kb = kc * 32 + kg * 8;
      const sh8 aH = *(const sh8*)(arh + kb);
      const sh8 aL = *(const sh8*)(arl + kb);
#pragma unroll
      for (int g = 0; g < 4; ++g) {
        const size_t bo = ((((size_t)(g * 64 + jt)) * (HH / 32) + kc) * 64 + lane) * 8;
        const sh8 bH = *(const sh8*)(win_h + bo);
        const sh8 bL = *(const sh8*)(win_l + bo);
        acc[g] = mfma_bf16(aH, bH, acc[g]);
        acc[g] = mfma_bf16(aH, bL, acc[g]);
        acc[g] = mfma_bf16(aL, bH, acc[g]);
      }
    }
  }

  {  // recurrent part, all modes: h(prev) x Whh^T
    const unsigned short* hrh = h_h + (size_t)arow * HH;
    const unsigned short* hrl = h_l + (size_t)arow * HH;
    for (int kc = 0; kc < HH / 32; ++kc) {
      const int kb = kc * 32 + kg * 8;
      const sh8 aH = *(const sh8*)(hrh + kb);
      const sh8 aL = *(const sh8*)(hrl + kb);
#pragma unroll
      for (int g = 0; g < 4; ++g) {
        const size_t bo = ((((size_t)(g * 64 + jt)) * (HH / 32) + kc) * 64 + lane) * 8;
        const sh8 bH = *(const sh8*)(whh_h + bo);
        const sh8 bL = *(const sh8*)(whh_l + bo);
        acc[g] = mfma_bf16(aH, bH, acc[g]);
        acc[g] = mfma_bf16(aH, bL, acc[g]);
        acc[g] = mfma_bf16(aL, bH, acc[g]);
      }
    }
  }

  // epilogue: D mapping col=lane&15, row=(lane>>4)*4+reg (m89-verified)
  const int j = jt * 16 + col;
#pragma unroll
  for (int r = 0; r < 4; ++r) {
    const int b = mt * 16 + kg * 4 + r;
    float zi = acc[0][r] + bias[j];
    float zf = acc[1][r] + bias[HH + j];
    float zg = acc[2][r] + bias[2 * HH + j];
    float zo = acc[3][r] + bias[3 * HH + j];
    if constexpr (MODE == 2) {
      const float ip = inp ? inp[(size_t)b * SS] : 0.f;  // prev decoder output (stride SS)
      zi += ip * w0col[j];
      zf += ip * w0col[HH + j];
      zg += ip * w0col[2 * HH + j];
      zo += ip * w0col[3 * HH + j];
    }
    const size_t idx = (size_t)b * HH + j;
    const float cold = cst[idx];
    const float ig = 1.f / (1.f + expf(-zi));
    const float fg = 1.f / (1.f + expf(-zf));
    const float og = 1.f / (1.f + expf(-zo));
    const float gt = tanhf(zg);
    const float cn = fg * cold + ig * gt;
    const float hn = og * tanhf(cn);
    cst[idx] = cn;
    const unsigned short hb = f2bf(hn);
    nh_h[idx] = hb;
    nh_l[idx] = f2bf(hn - bf2f(hb));  // h kept exactly as hi+lo pair
  }
#endif
}

// out[b] = h1[b,:] . fcW + fcb, written to d_out column s (stride SS)
__global__ __launch_bounds__(64) void fc_kernel(const unsigned short* __restrict__ h_h,
                                                const unsigned short* __restrict__ h_l,
                                                const float* __restrict__ fcw,
                                                const float* __restrict__ fcb,
                                                float* __restrict__ outp) {
  const int b = blockIdx.x;
  const int lane = threadIdx.x;
  const unsigned short* hh = h_h + (size_t)b * HH;
  const unsigned short* hl = h_l + (size_t)b * HH;
  float s = 0.f;
  for (int k = lane; k < HH; k += 64) s += (bf2f(hh[k]) + bf2f(hl[k])) * fcw[k];
  for (int o = 32; o > 0; o >>= 1) s += __shfl_down(s, o);
  if (lane == 0) outp[(size_t)b * SS] = s + fcb[0];
}

extern "C" void kernel_launch(void* const* d_in, const int* in_sizes, int n_in,
                              void* d_out, int out_size, void* d_ws, size_t ws_size,
                              hipStream_t stream) {
  (void)in_sizes; (void)n_in; (void)out_size; (void)ws_size;
  const float* x     = (const float*)d_in[0];
  const float* eWih0 = (const float*)d_in[1];
  const float* eWhh0 = (const float*)d_in[2];
  const float* eBih0 = (const float*)d_in[3];
  const float* eBhh0 = (const float*)d_in[4];
  const float* eWih1 = (const float*)d_in[5];
  const float* eWhh1 = (const float*)d_in[6];
  const float* eBih1 = (const float*)d_in[7];
  const float* eBhh1 = (const float*)d_in[8];
  const float* dWih0 = (const float*)d_in[9];   // (4096,1): used directly as fp32 rank-1 column
  const float* dWhh0 = (const float*)d_in[10];
  const float* dBih0 = (const float*)d_in[11];
  const float* dBhh0 = (const float*)d_in[12];
  const float* dWih1 = (const float*)d_in[13];
  const float* dWhh1 = (const float*)d_in[14];
  const float* dBih1 = (const float*)d_in[15];
  const float* dBhh1 = (const float*)d_in[16];
  const float* fcW   = (const float*)d_in[17];
  const float* fcB   = (const float*)d_in[18];
  float* out = (float*)d_out;  // (B, S) fp32

  char* base = (char*)d_ws;
  size_t off = 0;
  auto alloc = [&](size_t bytes) -> void* {
    void* p = base + off;
    off = (off + bytes + 255) & ~(size_t)255;
    return p;
  };

  // --- zero-initialized block first (single memset covers it) ---
  unsigned short* h0h[2]; unsigned short* h0l[2];
  unsigned short* h1h[2]; unsigned short* h1l[2];
  h0h[0] = (unsigned short*)alloc(BB * HH * 2);
  h0l[0] = (unsigned short*)alloc(BB * HH * 2);
  h1h[0] = (unsigned short*)alloc(BB * HH * 2);
  h1l[0] = (unsigned short*)alloc(BB * HH * 2);
  float* c0 = (float*)alloc(BB * HH * 4);
  float* c1 = (float*)alloc(BB * HH * 4);
  const size_t zbytes = off;
  // --- ping buffers (fully written before first read) ---
  h0h[1] = (unsigned short*)alloc(BB * HH * 2);
  h0l[1] = (unsigned short*)alloc(BB * HH * 2);
  h1h[1] = (unsigned short*)alloc(BB * HH * 2);
  h1l[1] = (unsigned short*)alloc(BB * HH * 2);
  // --- split/swizzled weights (~97 MB) ---
  unsigned short* wih0e_h = (unsigned short*)alloc(NG * INF * 2);
  unsigned short* wih0e_l = (unsigned short*)alloc(NG * INF * 2);
  unsigned short* whh0e_h = (unsigned short*)alloc((size_t)NG * HH * 2);
  unsigned short* whh0e_l = (unsigned short*)alloc((size_t)NG * HH * 2);
  unsigned short* wih1e_h = (unsigned short*)alloc((size_t)NG * HH * 2);
  unsigned short* wih1e_l = (unsigned short*)alloc((size_t)NG * HH * 2);
  unsigned short* whh1e_h = (unsigned short*)alloc((size_t)NG * HH * 2);
  unsigned short* whh1e_l = (unsigned short*)alloc((size_t)NG * HH * 2);
  unsigned short* whh0d_h = (unsigned short*)alloc((size_t)NG * HH * 2);
  unsigned short* whh0d_l = (unsigned short*)alloc((size_t)NG * HH * 2);
  unsigned short* wih1d_h = (unsigned short*)alloc((size_t)NG * HH * 2);
  unsigned short* wih1d_l = (unsigned short*)alloc((size_t)NG * HH * 2);
  unsigned short* whh1d_h = (unsigned short*)alloc((size_t)NG * HH * 2);
  unsigned short* whh1d_l = (unsigned short*)alloc((size_t)NG * HH * 2);
  float* bias0e = (float*)alloc(NG * 4);
  float* bias1e = (float*)alloc(NG * 4);
  float* bias0d = (float*)alloc(NG * 4);
  float* bias1d = (float*)alloc(NG * 4);

  // --- preprocessing (re-done every call: deterministic) ---
  hipMemsetAsync(base, 0, zbytes, stream);
  const int gb = (NG * HH + 255) / 256;
  prep_weight<<<gb, 256, 0, stream>>>(eWhh0, whh0e_h, whh0e_l, 10);
  prep_weight<<<gb, 256, 0, stream>>>(eWih1, wih1e_h, wih1e_l, 10);
  prep_weight<<<gb, 256, 0, stream>>>(eWhh1, whh1e_h, whh1e_l, 10);
  prep_weight<<<gb, 256, 0, stream>>>(dWhh0, whh0d_h, whh0d_l, 10);
  prep_weight<<<gb, 256, 0, stream>>>(dWih1, wih1d_h, wih1d_l, 10);
  prep_weight<<<gb, 256, 0, stream>>>(dWhh1, whh1d_h, whh1d_l, 10);
  prep_weight<<<(NG * INF + 255) / 256, 256, 0, stream>>>(eWih0, wih0e_h, wih0e_l, 6);
  const int gbias = (NG + 255) / 256;
  prep_bias<<<gbias, 256, 0, stream>>>(eBih0, eBhh0, bias0e);
  prep_bias<<<gbias, 256, 0, stream>>>(eBih1, eBhh1, bias1e);
  prep_bias<<<gbias, 256, 0, stream>>>(dBih0, dBhh0, bias0d);
  prep_bias<<<gbias, 256, 0, stream>>>(dBih1, dBhh1, bias1d);

  const dim3 gstep(64, 2);
  int p0 = 0, p1 = 0;

  // --- encoder: 512 steps, layer0 then layer1 (stream-ordered) ---
  for (int t = 0; t < TT; ++t) {
    lstm_step<0><<<gstep, 256, 0, stream>>>(
        x + (size_t)t * INF, TT * INF,
        nullptr, nullptr, nullptr,
        wih0e_h, wih0e_l, nullptr,
        whh0e_h, whh0e_l, bias0e,
        h0h[p0], h0l[p0], h0h[p0 ^ 1], h0l[p0 ^ 1], c0);
    p0 ^= 1;
    lstm_step<1><<<gstep, 256, 0, stream>>>(
        nullptr, 0,
        h0h[p0], h0l[p0], nullptr,
        wih1e_h, wih1e_l, nullptr,
        whh1e_h, whh1e_l, bias1e,
        h1h[p1], h1l[p1], h1h[p1 ^ 1], h1l[p1 ^ 1], c1);
    p1 ^= 1;
  }

  // --- autoregressive decoder: states continue from encoder finals ---
  for (int s = 0; s < SS; ++s) {
    lstm_step<2><<<gstep, 256, 0, stream>>>(
        nullptr, 0, nullptr, nullptr,
        s ? out + (s - 1) : nullptr,
        nullptr, nullptr, dWih0,
        whh0d_h, whh0d_l, bias0d,
        h0h[p0], h0l[p0], h0h[p0 ^ 1], h0l[p0 ^ 1], c0);
    p0 ^= 1;
    lstm_step<1><<<gstep, 256, 0, stream>>>(
        nullptr, 0,
        h0h[p0], h0l[p0], nullptr,
        wih1d_h, wih1d_l, nullptr,
        whh1d_h, whh1d_l, bias1d,
        h1h[p1], h1l[p1], h1h[p1 ^ 1], h1l[p1 ^ 1], c1);
    p1 ^= 1;
    fc_kernel<<<dim3(BB), 64, 0, stream>>>(h1h[p1], h1l[p1], fcW, fcB, out + s);
  }
}

// Round 5
// 30823.260 us; speedup vs baseline: 1.7787x; 1.7787x over previous
//
#include <hip/hip_runtime.h>
#include <cmath>
#include <cstdint>
#include <cstddef>

#define BB   128
#define TT   512
#define INF  64
#define HH   1024
#define NG   4096
#define SS   64
#define NBLK 192

// LDS layout (byte offsets); total 155648 B = 152 KB
#define SWHI_B 0          // hi weights: 4 gates x 32 kc x 64 lanes x 16B = 131072
#define SLO_B  131072     // lo double-buffer: 2 x 8192 B
#define SWX_B  147456     // Wih0-hi (enc L0 only): 8192 B
#define LDS_BYTES 155648

typedef __attribute__((ext_vector_type(8))) short sh8;
typedef __attribute__((ext_vector_type(4))) float f32x4;

__device__ __forceinline__ float bf2f(unsigned short u) {
  unsigned int i = ((unsigned int)u) << 16;
  return __builtin_bit_cast(float, i);
}
__device__ __forceinline__ unsigned short f2bf(float f) {
  unsigned int u = __builtin_bit_cast(unsigned int, f);
  u += 0x7FFFu + ((u >> 16) & 1u);
  return (unsigned short)(u >> 16);
}
__device__ __forceinline__ float sigm(float x) { return 1.f / (1.f + __expf(-x)); }
__device__ __forceinline__ float tanh_f(float x) {
  x = fminf(15.f, fmaxf(-15.f, x));
  const float e = __expf(2.f * x);
  return (e - 1.f) / (e + 1.f);
}
__device__ __forceinline__ sh8 ld8(const unsigned short* p) { return *(const sh8*)p; }

#if defined(__HIP_DEVICE_COMPILE__)
// Device pass: real MFMA via SFINAE shim (operand type short8 vs __bf16x8
// differs across compiler versions).
typedef __attribute__((ext_vector_type(8))) __bf16 bf8;
template <class T> T&& my_declval();
template <class V, class = void> struct mfma_takes { static constexpr bool value = false; };
template <class V>
struct mfma_takes<V, decltype((void)__builtin_amdgcn_mfma_f32_16x16x32_bf16(
                        my_declval<V>(), my_declval<V>(), my_declval<f32x4>(), 0, 0, 0))> {
  static constexpr bool value = true;
};
template <class V>
__device__ __forceinline__ f32x4 mfma_imp(V a, V b, f32x4 c) {
  return __builtin_amdgcn_mfma_f32_16x16x32_bf16(a, b, c, 0, 0, 0);
}
__device__ __forceinline__ f32x4 mfma_bf16(sh8 a, sh8 b, f32x4 c) {
  if constexpr (mfma_takes<sh8>::value) {
    return mfma_imp<sh8>(a, b, c);
  } else {
    return mfma_imp<bf8>(__builtin_bit_cast(bf8, a), __builtin_bit_cast(bf8, b), c);
  }
}
#else
// Host pass: semantic-check stub only; never codegen'd.
__device__ __forceinline__ f32x4 mfma_bf16(sh8, sh8, f32x4 c) { return c; }
#endif

// ---------- preprocessing kernels ----------
// fp32 [NG][K] row-major -> split bf16 hi/lo in MFMA B-fragment order:
// 16B-unit index = (( (n>>4)*(K/32) + (k>>5) )*64 + ((k>>3)&3)*16 + (n&15)), elem k&7.
__global__ __launch_bounds__(256) void prep_weight(const float* __restrict__ W,
                                                   unsigned short* __restrict__ hi,
                                                   unsigned short* __restrict__ lo,
                                                   int lk) {
  const int K = 1 << lk;
  const int idx = blockIdx.x * 256 + threadIdx.x;
  if (idx >= (NG << lk)) return;
  const int n = idx >> lk;
  const int k = idx & (K - 1);
  const float v = W[idx];
  const unsigned short h = f2bf(v);
  const unsigned short l = f2bf(v - bf2f(h));
  const int nkch = K >> 5;
  const size_t o =
      ((((size_t)(n >> 4) * nkch + (k >> 5)) * 64) + (((k >> 3) & 3) * 16) + (n & 15)) * 8 +
      (k & 7);
  hi[o] = h;
  lo[o] = l;
}

__global__ __launch_bounds__(256) void prep_bias(const float* __restrict__ a,
                                                 const float* __restrict__ b,
                                                 float* __restrict__ o) {
  const int i = blockIdx.x * 256 + threadIdx.x;
  if (i < NG) o[i] = a[i] + b[i];
}

__global__ __launch_bounds__(256) void init_out(float* __restrict__ out_tmp,
                                                const float* __restrict__ fcb) {
  const int i = blockIdx.x * 256 + threadIdx.x;
  if (i < SS * BB) out_tmp[i] = fcb[0];
}

// ---------- persistent kernel (manual co-residency: 152KB LDS -> 1 block/CU,
// grid 192 <= 256 CUs, so all blocks resident; custom grid barrier below) ----
struct KArgs {
  const float* x;
  const unsigned short *wih0_h, *wih0_l;
  const unsigned short *whh0e_h, *whh0e_l;
  const unsigned short *wih1e_h, *wih1e_l;
  const unsigned short *whh1e_h, *whh1e_l;
  const unsigned short *whh0d_h, *whh0d_l;
  const unsigned short *wih1d_h, *wih1d_l;
  const unsigned short *whh1d_h, *whh1d_l;
  const float *bias0e, *bias1e, *bias0d, *bias1d;
  const float *w0col, *fcw, *fcb;
  unsigned short *h0h0, *h0h1, *h0l0, *h0l1;
  unsigned short *h1h0, *h1h1, *h1l0, *h1l1;
  float *zb0, *zb1;
  float *out_tmp;
  float *outp;
  int *bar_cnt, *bar_gen;
};

__device__ __forceinline__ void grid_barrier(int* cnt, int* gen) {
  __syncthreads();
  if (threadIdx.x == 0) {
    __threadfence();  // release
    int g = __hip_atomic_load(gen, __ATOMIC_RELAXED, __HIP_MEMORY_SCOPE_AGENT);
    if (__hip_atomic_fetch_add(cnt, 1, __ATOMIC_ACQ_REL, __HIP_MEMORY_SCOPE_AGENT) == NBLK - 1) {
      __hip_atomic_store(cnt, 0, __ATOMIC_RELAXED, __HIP_MEMORY_SCOPE_AGENT);
      __hip_atomic_fetch_add(gen, 1, __ATOMIC_ACQ_REL, __HIP_MEMORY_SCOPE_AGENT);
    } else {
      while (__hip_atomic_load(gen, __ATOMIC_RELAXED, __HIP_MEMORY_SCOPE_AGENT) == g) {
        __builtin_amdgcn_s_sleep(2);
      }
    }
    __threadfence();  // acquire
  }
  __syncthreads();
}

// copy this block's hi-weight slice (4 x 32KB contiguous segments) into LDS
__device__ __forceinline__ void load_whi(unsigned short* lds, const unsigned short* hi, int jt) {
#pragma unroll
  for (int g = 0; g < 4; ++g) {
    const uint4* src = (const uint4*)(hi + ((size_t)(g * 64 + jt) * 32) * 512);
    uint4* dst = (uint4*)((char*)lds + SWHI_B + g * 32768);
    for (int u = threadIdx.x; u < 2048; u += 256) dst[u] = src[u];
  }
}
__device__ __forceinline__ void load_wx(unsigned short* lds, const unsigned short* hi, int jt) {
  for (int u = threadIdx.x; u < 512; u += 256) {
    const int g = u >> 7, rem = u & 127;
    const uint4* src = (const uint4*)(hi + ((size_t)(g * 64 + jt) * 128 + rem) * 8);
    ((uint4*)((char*)lds + SWX_B))[u] = *src;
  }
}

__device__ __forceinline__ const uint4* lo_src(const unsigned short* glo, int jt, int c, int f) {
  const int g = f >> 7, rem = f & 127, kcl = rem >> 6, l = rem & 63;
  const size_t u16 = ((size_t)((g * 64 + jt) * 32) + c * 2 + kcl) * 64 + l;
  return (const uint4*)(glo + u16 * 8);
}

// acc += A(hi,lo)[128xHH] x B(jt-slice)^T; B-hi from LDS, B-lo staged via LDS dbuf
__device__ __forceinline__ void gemm1024(f32x4 (*acc)[4],
                                         const unsigned short* __restrict__ ah,
                                         const unsigned short* __restrict__ al,
                                         const unsigned short* __restrict__ glo,
                                         int jt, unsigned short* lds) {
  const int tid = threadIdx.x;
  const int lane = tid & 63, wid = tid >> 6;
  const int kg = lane >> 4;
  const int r0 = wid * 32 + (lane & 15), r1 = r0 + 16;
  const unsigned short* a0h = ah + r0 * HH;
  const unsigned short* a0l = al + r0 * HH;
  const unsigned short* a1h = ah + r1 * HH;
  const unsigned short* a1l = al + r1 * HH;

  {  // stage chunk 0
    uint4 s0 = *lo_src(glo, jt, 0, tid);
    uint4 s1 = *lo_src(glo, jt, 0, tid + 256);
    *(uint4*)((char*)lds + SLO_B + tid * 16) = s0;
    *(uint4*)((char*)lds + SLO_B + 4096 + tid * 16) = s1;
  }
  __syncthreads();

  for (int c = 0; c < 16; ++c) {
    uint4 n0, n1;
    if (c < 15) {  // issue next-chunk loads early (overlap with compute)
      n0 = *lo_src(glo, jt, c + 1, tid);
      n1 = *lo_src(glo, jt, c + 1, tid + 256);
    }
#pragma unroll
    for (int kcl = 0; kcl < 2; ++kcl) {
      const int kc = c * 2 + kcl;
      const int kb = kc * 32 + kg * 8;
      const sh8 aH0 = ld8(a0h + kb), aL0 = ld8(a0l + kb);
      const sh8 aH1 = ld8(a1h + kb), aL1 = ld8(a1l + kb);
#pragma unroll
      for (int g = 0; g < 4; ++g) {
        const sh8 bH = ld8(lds + (g * 32 + kc) * 512 + lane * 8);
        const sh8 bL =
            ld8(lds + SLO_B / 2 + (c & 1) * 4096 + (g * 2 + kcl) * 512 + lane * 8);
        acc[0][g] = mfma_bf16(aH0, bH, acc[0][g]);
        acc[0][g] = mfma_bf16(aL0, bH, acc[0][g]);
        acc[0][g] = mfma_bf16(aH0, bL, acc[0][g]);
        acc[1][g] = mfma_bf16(aH1, bH, acc[1][g]);
        acc[1][g] = mfma_bf16(aL1, bH, acc[1][g]);
        acc[1][g] = mfma_bf16(aH1, bL, acc[1][g]);
      }
    }
    if (c < 15) {
      const int nb = (c + 1) & 1;
      *(uint4*)((char*)lds + SLO_B + nb * 8192 + tid * 16) = n0;
      *(uint4*)((char*)lds + SLO_B + nb * 8192 + 4096 + tid * 16) = n1;
    }
    __syncthreads();
  }
}

// encoder L0 extra: x(fp32, K=64) x Wih0; hi in LDS, lo streamed
__device__ __forceinline__ void gemm_x(f32x4 (*acc)[4], const float* __restrict__ x, int t,
                                       const unsigned short* __restrict__ wxl, int jt,
                                       const unsigned short* lds) {
  const int tid = threadIdx.x;
  const int lane = tid & 63, wid = tid >> 6;
  const int kg = lane >> 4;
  const int r0 = wid * 32 + (lane & 15), r1 = r0 + 16;
  const float* xr0 = x + (size_t)r0 * (TT * INF) + t * INF;
  const float* xr1 = x + (size_t)r1 * (TT * INF) + t * INF;
#pragma unroll
  for (int kc2 = 0; kc2 < 2; ++kc2) {
    const int kb = kc2 * 32 + kg * 8;
    sh8 xh0, xl0, xh1, xl1;
#pragma unroll
    for (int e = 0; e < 8; ++e) {
      const float v0 = xr0[kb + e];
      const unsigned short h0 = f2bf(v0);
      xh0[e] = (short)h0;
      xl0[e] = (short)f2bf(v0 - bf2f(h0));
      const float v1 = xr1[kb + e];
      const unsigned short h1 = f2bf(v1);
      xh1[e] = (short)h1;
      xl1[e] = (short)f2bf(v1 - bf2f(h1));
    }
#pragma unroll
    for (int g = 0; g < 4; ++g) {
      const sh8 bH = ld8(lds + SWX_B / 2 + (g * 2 + kc2) * 512 + lane * 8);
      const sh8 bL = ld8(wxl + (((size_t)(g * 64 + jt) * 2 + kc2) * 64 + lane) * 8);
      acc[0][g] = mfma_bf16(xh0, bH, acc[0][g]);
      acc[0][g] = mfma_bf16(xl0, bH, acc[0][g]);
      acc[0][g] = mfma_bf16(xh0, bL, acc[0][g]);
      acc[1][g] = mfma_bf16(xh1, bH, acc[1][g]);
      acc[1][g] = mfma_bf16(xl1, bH, acc[1][g]);
      acc[1][g] = mfma_bf16(xh1, bL, acc[1][g]);
    }
  }
}

__device__ __forceinline__ void store_z(f32x4 (*acc)[4], float* zb, int jt) {
  const int tid = threadIdx.x;
  const int lane = tid & 63, wid = tid >> 6;
  const int col = lane & 15, kg = lane >> 4;
#pragma unroll
  for (int m = 0; m < 2; ++m)
#pragma unroll
    for (int g = 0; g < 4; ++g) {
      const int row = g * HH + jt * 16 + col;
      const int bq = (wid * 2 + m) * 16 + kg * 4;
      *(f32x4*)(zb + (size_t)row * BB + bq) = acc[m][g];
    }
}
__device__ __forceinline__ void add_z(f32x4 (*acc)[4], const float* zb, int jt) {
  const int tid = threadIdx.x;
  const int lane = tid & 63, wid = tid >> 6;
  const int col = lane & 15, kg = lane >> 4;
#pragma unroll
  for (int m = 0; m < 2; ++m)
#pragma unroll
    for (int g = 0; g < 4; ++g) {
      const int row = g * HH + jt * 16 + col;
      const int bq = (wid * 2 + m) * 16 + kg * 4;
      acc[m][g] += *(const f32x4*)(zb + (size_t)row * BB + bq);
    }
}

// MODE: 0 plain, 1 rank-1 decoder input, 2 FC partial output
template <int MODE>
__device__ __forceinline__ void cellfin(f32x4 (*acc)[4], float (*creg)[4],
                                        const float* __restrict__ bias, int jt,
                                        unsigned short* __restrict__ nhh,
                                        unsigned short* __restrict__ nhl,
                                        const float* w0g, const float* inp_vec, float fcwj,
                                        float* fc_out) {
  const int tid = threadIdx.x;
  const int lane = tid & 63, wid = tid >> 6;
  const int col = lane & 15, kg = lane >> 4;
  const int j = jt * 16 + col;
  const float b0 = bias[j], b1 = bias[HH + j], b2 = bias[2 * HH + j], b3 = bias[3 * HH + j];
#pragma unroll
  for (int m = 0; m < 2; ++m) {
#pragma unroll
    for (int r = 0; r < 4; ++r) {
      const int b = (wid * 2 + m) * 16 + kg * 4 + r;
      float zi = acc[m][0][r] + b0;
      float zf = acc[m][1][r] + b1;
      float zg = acc[m][2][r] + b2;
      float zo = acc[m][3][r] + b3;
      if constexpr (MODE == 1) {
        const float ip = inp_vec ? inp_vec[b] : 0.f;
        zi += ip * w0g[0];
        zf += ip * w0g[1];
        zg += ip * w0g[2];
        zo += ip * w0g[3];
      }
      const float cn = sigm(zf) * creg[m][r] + sigm(zi) * tanh_f(zg);
      const float hn = sigm(zo) * tanh_f(cn);
      creg[m][r] = cn;
      const unsigned short hb = f2bf(hn);
      nhh[b * HH + j] = hb;
      nhl[b * HH + j] = f2bf(hn - bf2f(hb));
      if constexpr (MODE == 2) {
        float cb = hn * fcwj;
        cb += __shfl_xor(cb, 1);
        cb += __shfl_xor(cb, 2);
        cb += __shfl_xor(cb, 4);
        cb += __shfl_xor(cb, 8);
        if (col == 0) atomicAdd(fc_out + b, cb);
      }
    }
  }
}

__device__ __forceinline__ void zacc(f32x4 (*acc)[4]) {
#pragma unroll
  for (int m = 0; m < 2; ++m)
#pragma unroll
    for (int g = 0; g < 4; ++g) acc[m][g] = f32x4{0.f, 0.f, 0.f, 0.f};
}

__global__ __launch_bounds__(256, 1) void seq2seq_coop(KArgs a) {
  extern __shared__ unsigned short lds[];
  const int bid = blockIdx.x;
  const int role = bid >> 6;
  const int jt = bid & 63;
  const int tid = threadIdx.x;

  unsigned short* h0h[2] = {a.h0h0, a.h0h1};
  unsigned short* h0l[2] = {a.h0l0, a.h0l1};
  unsigned short* h1h[2] = {a.h1h0, a.h1h1};
  unsigned short* h1l[2] = {a.h1l0, a.h1l1};
  float* zb[2] = {a.zb0, a.zb1};

  if (role == 0) {
    load_whi(lds, a.whh0e_h, jt);
    load_wx(lds, a.wih0_h, jt);
  } else if (role == 1) {
    load_whi(lds, a.wih1e_h, jt);
  } else {
    load_whi(lds, a.whh1e_h, jt);
  }
  __syncthreads();

  float creg[2][4] = {};

  // ---- encoder: software-pipelined, 1 barrier per iteration ----
  for (int i = 0; i < TT + 2; ++i) {
    if (role == 0) {
      if (i < TT) {
        f32x4 acc[2][4];
        zacc(acc);
        gemm1024(acc, h0h[(i + 1) & 1], h0l[(i + 1) & 1], a.whh0e_l, jt, lds);
        gemm_x(acc, a.x, i, a.wih0_l, jt, lds);
        cellfin<0>(acc, creg, a.bias0e, jt, h0h[i & 1], h0l[i & 1], nullptr, nullptr, 0.f,
                   nullptr);
      }
    } else if (role == 1) {
      if (i >= 1 && i <= TT) {
        const int s = i - 1;
        f32x4 acc[2][4];
        zacc(acc);
        gemm1024(acc, h0h[s & 1], h0l[s & 1], a.wih1e_l, jt, lds);
        store_z(acc, zb[s & 1], jt);
      }
    } else {
      if (i >= 2) {
        const int s = i - 2;
        f32x4 acc[2][4];
        zacc(acc);
        gemm1024(acc, h1h[(s + 1) & 1], h1l[(s + 1) & 1], a.whh1e_l, jt, lds);
        add_z(acc, zb[s & 1], jt);
        cellfin<0>(acc, creg, a.bias1e, jt, h1h[s & 1], h1l[s & 1], nullptr, nullptr, 0.f,
                   nullptr);
      }
    }
    grid_barrier(a.bar_cnt, a.bar_gen);
  }

  // ---- decoder: reload LDS weights, 3 phases per step ----
  if (role == 0) load_whi(lds, a.whh0d_h, jt);
  else if (role == 1) load_whi(lds, a.wih1d_h, jt);
  else load_whi(lds, a.whh1d_h, jt);
  __syncthreads();

  float w0g[4] = {0.f, 0.f, 0.f, 0.f};
  float fcwj = 0.f;
  if (role == 0) {
    const int j = jt * 16 + (tid & 15);
    w0g[0] = a.w0col[j];
    w0g[1] = a.w0col[HH + j];
    w0g[2] = a.w0col[2 * HH + j];
    w0g[3] = a.w0col[3 * HH + j];
  }
  if (role == 2) fcwj = a.fcw[jt * 16 + (tid & 15)];

  for (int s = 0; s < SS; ++s) {
    if (role == 0) {
      f32x4 acc[2][4];
      zacc(acc);
      gemm1024(acc, h0h[(s + 1) & 1], h0l[(s + 1) & 1], a.whh0d_l, jt, lds);
      cellfin<1>(acc, creg, a.bias0d, jt, h0h[s & 1], h0l[s & 1], w0g,
                 s ? a.out_tmp + (s - 1) * BB : nullptr, 0.f, nullptr);
    }
    grid_barrier(a.bar_cnt, a.bar_gen);
    if (role == 1) {
      f32x4 acc[2][4];
      zacc(acc);
      gemm1024(acc, h0h[s & 1], h0l[s & 1], a.wih1d_l, jt, lds);
      store_z(acc, zb[0], jt);
    }
    grid_barrier(a.bar_cnt, a.bar_gen);
    if (role == 2) {
      f32x4 acc[2][4];
      zacc(acc);
      gemm1024(acc, h1h[(s + 1) & 1], h1l[(s + 1) & 1], a.whh1d_l, jt, lds);
      add_z(acc, zb[0], jt);
      cellfin<2>(acc, creg, a.bias1d, jt, h1h[s & 1], h1l[s & 1], nullptr, nullptr, fcwj,
                 a.out_tmp + s * BB);
    }
    grid_barrier(a.bar_cnt, a.bar_gen);
  }

  // ---- final: out_tmp (S,B) -> d_out (B,S) ----
  if (bid < 32) {
    const int gi = bid * 256 + tid;  // gi = b*64 + s
    const int b = gi >> 6, s2 = gi & 63;
    a.outp[gi] = a.out_tmp[s2 * BB + b];
  }
}

extern "C" void kernel_launch(void* const* d_in, const int* in_sizes, int n_in,
                              void* d_out, int out_size, void* d_ws, size_t ws_size,
                              hipStream_t stream) {
  (void)in_sizes; (void)n_in; (void)out_size; (void)ws_size;
  const float* x     = (const float*)d_in[0];
  const float* eWih0 = (const float*)d_in[1];
  const float* eWhh0 = (const float*)d_in[2];
  const float* eBih0 = (const float*)d_in[3];
  const float* eBhh0 = (const float*)d_in[4];
  const float* eWih1 = (const float*)d_in[5];
  const float* eWhh1 = (const float*)d_in[6];
  const float* eBih1 = (const float*)d_in[7];
  const float* eBhh1 = (const float*)d_in[8];
  const float* dWih0 = (const float*)d_in[9];
  const float* dWhh0 = (const float*)d_in[10];
  const float* dBih0 = (const float*)d_in[11];
  const float* dBhh0 = (const float*)d_in[12];
  const float* dWih1 = (const float*)d_in[13];
  const float* dWhh1 = (const float*)d_in[14];
  const float* dBih1 = (const float*)d_in[15];
  const float* dBhh1 = (const float*)d_in[16];
  const float* fcW   = (const float*)d_in[17];
  const float* fcB   = (const float*)d_in[18];
  float* out = (float*)d_out;

  char* base = (char*)d_ws;
  size_t off = 0;
  auto alloc = [&](size_t bytes) -> void* {
    void* p = base + off;
    off = (off + bytes + 255) & ~(size_t)255;
    return p;
  };

  // zero-initialized block (one memset): h buffers + barrier
  unsigned short* h0h0 = (unsigned short*)alloc(BB * HH * 2);
  unsigned short* h0h1 = (unsigned short*)alloc(BB * HH * 2);
  unsigned short* h0l0 = (unsigned short*)alloc(BB * HH * 2);
  unsigned short* h0l1 = (unsigned short*)alloc(BB * HH * 2);
  unsigned short* h1h0 = (unsigned short*)alloc(BB * HH * 2);
  unsigned short* h1h1 = (unsigned short*)alloc(BB * HH * 2);
  unsigned short* h1l0 = (unsigned short*)alloc(BB * HH * 2);
  unsigned short* h1l1 = (unsigned short*)alloc(BB * HH * 2);
  int* bar = (int*)alloc(256);
  const size_t zbytes = off;

  float* zb0 = (float*)alloc((size_t)NG * BB * 4);
  float* zb1 = (float*)alloc((size_t)NG * BB * 4);
  float* out_tmp = (float*)alloc(SS * BB * 4);

  unsigned short* wih0_h = (unsigned short*)alloc((size_t)NG * INF * 2);
  unsigned short* wih0_l = (unsigned short*)alloc((size_t)NG * INF * 2);
  auto big = [&]() { return (unsigned short*)alloc((size_t)NG * HH * 2); };
  unsigned short *whh0e_h = big(), *whh0e_l = big();
  unsigned short *wih1e_h = big(), *wih1e_l = big();
  unsigned short *whh1e_h = big(), *whh1e_l = big();
  unsigned short *whh0d_h = big(), *whh0d_l = big();
  unsigned short *wih1d_h = big(), *wih1d_l = big();
  unsigned short *whh1d_h = big(), *whh1d_l = big();
  float* bias0e = (float*)alloc(NG * 4);
  float* bias1e = (float*)alloc(NG * 4);
  float* bias0d = (float*)alloc(NG * 4);
  float* bias1d = (float*)alloc(NG * 4);

  (void)hipMemsetAsync(base, 0, zbytes, stream);
  const int gb = (NG * HH + 255) / 256;
  prep_weight<<<gb, 256, 0, stream>>>(eWhh0, whh0e_h, whh0e_l, 10);
  prep_weight<<<gb, 256, 0, stream>>>(eWih1, wih1e_h, wih1e_l, 10);
  prep_weight<<<gb, 256, 0, stream>>>(eWhh1, whh1e_h, whh1e_l, 10);
  prep_weight<<<gb, 256, 0, stream>>>(dWhh0, whh0d_h, whh0d_l, 10);
  prep_weight<<<gb, 256, 0, stream>>>(dWih1, wih1d_h, wih1d_l, 10);
  prep_weight<<<gb, 256, 0, stream>>>(dWhh1, whh1d_h, whh1d_l, 10);
  prep_weight<<<(NG * INF + 255) / 256, 256, 0, stream>>>(eWih0, wih0_h, wih0_l, 6);
  const int gbias = (NG + 255) / 256;
  prep_bias<<<gbias, 256, 0, stream>>>(eBih0, eBhh0, bias0e);
  prep_bias<<<gbias, 256, 0, stream>>>(eBih1, eBhh1, bias1e);
  prep_bias<<<gbias, 256, 0, stream>>>(dBih0, dBhh0, bias0d);
  prep_bias<<<gbias, 256, 0, stream>>>(dBih1, dBhh1, bias1d);
  init_out<<<(SS * BB + 255) / 256, 256, 0, stream>>>(out_tmp, fcB);

  KArgs ka;
  ka.x = x;
  ka.wih0_h = wih0_h; ka.wih0_l = wih0_l;
  ka.whh0e_h = whh0e_h; ka.whh0e_l = whh0e_l;
  ka.wih1e_h = wih1e_h; ka.wih1e_l = wih1e_l;
  ka.whh1e_h = whh1e_h; ka.whh1e_l = whh1e_l;
  ka.whh0d_h = whh0d_h; ka.whh0d_l = whh0d_l;
  ka.wih1d_h = wih1d_h; ka.wih1d_l = wih1d_l;
  ka.whh1d_h = whh1d_h; ka.whh1d_l = whh1d_l;
  ka.bias0e = bias0e; ka.bias1e = bias1e; ka.bias0d = bias0d; ka.bias1d = bias1d;
  ka.w0col = dWih0; ka.fcw = fcW; ka.fcb = fcB;
  ka.h0h0 = h0h0; ka.h0h1 = h0h1; ka.h0l0 = h0l0; ka.h0l1 = h0l1;
  ka.h1h0 = h1h0; ka.h1h1 = h1h1; ka.h1l0 = h1l0; ka.h1l1 = h1l1;
  ka.zb0 = zb0; ka.zb1 = zb1;
  ka.out_tmp = out_tmp;
  ka.outp = out;
  ka.bar_cnt = bar; ka.bar_gen = bar + 32;

  (void)hipFuncSetAttribute((const void*)seq2seq_coop,
                            hipFuncAttributeMaxDynamicSharedMemorySize, LDS_BYTES);
  // Plain launch: 152KB LDS -> 1 block/CU, 192 blocks <= 256 CUs -> all
  // resident; the hand-rolled grid barrier needs no cooperative-launch API.
  seq2seq_coop<<<dim3(NBLK), dim3(256), LDS_BYTES, stream>>>(ka);
}

// Round 6
// 27258.057 us; speedup vs baseline: 2.0114x; 1.1308x over previous
//
#include <hip/hip_runtime.h>
#include <cmath>
#include <cstdint>
#include <cstddef>

#define BB   128
#define TT   512
#define INF  64
#define HH   1024
#define NG   4096
#define SS   64
#define NBLK 192
#define COORD 64   // coordinator block: role 1 (lightest), jt 0

// LDS layout (byte offsets); total 155648 B = 152 KB
#define SWHI_B 0          // hi weights: 4 gates x 32 kc x 64 lanes x 16B = 131072
#define SLO_B  131072     // lo double-buffer: 2 x 8192 B
#define SWX_B  147456     // Wih0-hi (enc L0 only): 8192 B
#define LDS_BYTES 155648

typedef __attribute__((ext_vector_type(8))) short sh8;
typedef __attribute__((ext_vector_type(4))) float f32x4;

__device__ __forceinline__ float bf2f(unsigned short u) {
  unsigned int i = ((unsigned int)u) << 16;
  return __builtin_bit_cast(float, i);
}
__device__ __forceinline__ unsigned short f2bf(float f) {
  unsigned int u = __builtin_bit_cast(unsigned int, f);
  u += 0x7FFFu + ((u >> 16) & 1u);
  return (unsigned short)(u >> 16);
}
__device__ __forceinline__ float sigm(float x) { return 1.f / (1.f + __expf(-x)); }
__device__ __forceinline__ float tanh_f(float x) {
  x = fminf(15.f, fmaxf(-15.f, x));
  const float e = __expf(2.f * x);
  return (e - 1.f) / (e + 1.f);
}
__device__ __forceinline__ sh8 ld8(const unsigned short* p) { return *(const sh8*)p; }

#if defined(__HIP_DEVICE_COMPILE__)
// Device pass: real MFMA via SFINAE shim (operand type short8 vs __bf16x8
// differs across compiler versions).
typedef __attribute__((ext_vector_type(8))) __bf16 bf8;
template <class T> T&& my_declval();
template <class V, class = void> struct mfma_takes { static constexpr bool value = false; };
template <class V>
struct mfma_takes<V, decltype((void)__builtin_amdgcn_mfma_f32_16x16x32_bf16(
                        my_declval<V>(), my_declval<V>(), my_declval<f32x4>(), 0, 0, 0))> {
  static constexpr bool value = true;
};
template <class V>
__device__ __forceinline__ f32x4 mfma_imp(V a, V b, f32x4 c) {
  return __builtin_amdgcn_mfma_f32_16x16x32_bf16(a, b, c, 0, 0, 0);
}
__device__ __forceinline__ f32x4 mfma_bf16(sh8 a, sh8 b, f32x4 c) {
  if constexpr (mfma_takes<sh8>::value) {
    return mfma_imp<sh8>(a, b, c);
  } else {
    return mfma_imp<bf8>(__builtin_bit_cast(bf8, a), __builtin_bit_cast(bf8, b), c);
  }
}
#else
// Host pass: semantic-check stub only; never codegen'd.
__device__ __forceinline__ f32x4 mfma_bf16(sh8, sh8, f32x4 c) { return c; }
#endif

// ---------- preprocessing kernels ----------
// fp32 [NG][K] row-major -> split bf16 hi/lo in MFMA B-fragment order:
// 16B-unit index = (( (n>>4)*(K/32) + (k>>5) )*64 + ((k>>3)&3)*16 + (n&15)), elem k&7.
__global__ __launch_bounds__(256) void prep_weight(const float* __restrict__ W,
                                                   unsigned short* __restrict__ hi,
                                                   unsigned short* __restrict__ lo,
                                                   int lk) {
  const int K = 1 << lk;
  const int idx = blockIdx.x * 256 + threadIdx.x;
  if (idx >= (NG << lk)) return;
  const int n = idx >> lk;
  const int k = idx & (K - 1);
  const float v = W[idx];
  const unsigned short h = f2bf(v);
  const unsigned short l = f2bf(v - bf2f(h));
  const int nkch = K >> 5;
  const size_t o =
      ((((size_t)(n >> 4) * nkch + (k >> 5)) * 64) + (((k >> 3) & 3) * 16) + (n & 15)) * 8 +
      (k & 7);
  hi[o] = h;
  lo[o] = l;
}

__global__ __launch_bounds__(256) void prep_bias(const float* __restrict__ a,
                                                 const float* __restrict__ b,
                                                 float* __restrict__ o) {
  const int i = blockIdx.x * 256 + threadIdx.x;
  if (i < NG) o[i] = a[i] + b[i];
}

__global__ __launch_bounds__(256) void init_out(float* __restrict__ out_tmp,
                                                const float* __restrict__ fcb) {
  const int i = blockIdx.x * 256 + threadIdx.x;
  if (i < SS * BB) out_tmp[i] = fcb[0];
}

// ---------- persistent kernel (manual co-residency: 152KB LDS -> 1 block/CU,
// grid 192 <= 256 CUs, so all blocks resident) ----------
struct KArgs {
  const float* x;
  const unsigned short *wih0_h, *wih0_l;
  const unsigned short *whh0e_h, *whh0e_l;
  const unsigned short *wih1e_h, *wih1e_l;
  const unsigned short *whh1e_h, *whh1e_l;
  const unsigned short *whh0d_h, *whh0d_l;
  const unsigned short *wih1d_h, *wih1d_l;
  const unsigned short *whh1d_h, *whh1d_l;
  const float *bias0e, *bias1e, *bias0d, *bias1d;
  const float *w0col, *fcw, *fcb;
  unsigned short *h0h0, *h0h1, *h0l0, *h0l1;
  unsigned short *h1h0, *h1h1, *h1l0, *h1l1;
  float *zb0, *zb1;
  float *out_tmp;
  float *outp;
  int *arrive;  // NBLK slots, stride 16 ints (64B) each
  int *go;      // 1 slot
};

// Distributed grid barrier: per-block release-store to own arrive slot (no
// RMW contention), coordinator block aggregates with 192 polling threads and
// release-stores a go flag; waiters poll relaxed then one acquire load.
// `it` must increase monotonically across calls (same sequence in all blocks).
__device__ __forceinline__ void gbar(int* arrive, int* go, int it, int bid) {
  __syncthreads();
  const int tid = threadIdx.x;
  if (bid == COORD) {
    if (tid == 0)
      __hip_atomic_store(&arrive[COORD * 16], it, __ATOMIC_RELEASE, __HIP_MEMORY_SCOPE_AGENT);
    if (tid < NBLK) {
      while (__hip_atomic_load(&arrive[tid * 16], __ATOMIC_RELAXED, __HIP_MEMORY_SCOPE_AGENT) < it)
        __builtin_amdgcn_s_sleep(1);
    }
    __syncthreads();
    if (tid == 0) {
      __hip_atomic_store(go, it, __ATOMIC_RELEASE, __HIP_MEMORY_SCOPE_AGENT);
      (void)__hip_atomic_load(go, __ATOMIC_ACQUIRE, __HIP_MEMORY_SCOPE_AGENT);
    }
  } else {
    if (tid == 0) {
      __hip_atomic_store(&arrive[bid * 16], it, __ATOMIC_RELEASE, __HIP_MEMORY_SCOPE_AGENT);
      while (__hip_atomic_load(go, __ATOMIC_RELAXED, __HIP_MEMORY_SCOPE_AGENT) < it)
        __builtin_amdgcn_s_sleep(2);
      (void)__hip_atomic_load(go, __ATOMIC_ACQUIRE, __HIP_MEMORY_SCOPE_AGENT);
    }
  }
  __syncthreads();
}

// copy this block's hi-weight slice (4 x 32KB contiguous segments) into LDS
__device__ __forceinline__ void load_whi(unsigned short* lds, const unsigned short* hi, int jt) {
#pragma unroll
  for (int g = 0; g < 4; ++g) {
    const uint4* src = (const uint4*)(hi + ((size_t)(g * 64 + jt) * 32) * 512);
    uint4* dst = (uint4*)((char*)lds + SWHI_B + g * 32768);
    for (int u = threadIdx.x; u < 2048; u += 256) dst[u] = src[u];
  }
}
__device__ __forceinline__ void load_wx(unsigned short* lds, const unsigned short* hi, int jt) {
  for (int u = threadIdx.x; u < 512; u += 256) {
    const int g = u >> 7, rem = u & 127;
    const uint4* src = (const uint4*)(hi + ((size_t)(g * 64 + jt) * 128 + rem) * 8);
    ((uint4*)((char*)lds + SWX_B))[u] = *src;
  }
}

__device__ __forceinline__ const uint4* lo_src(const unsigned short* glo, int jt, int c, int f) {
  const int g = f >> 7, rem = f & 127, kcl = rem >> 6, l = rem & 63;
  const size_t u16 = ((size_t)((g * 64 + jt) * 32) + c * 2 + kcl) * 64 + l;
  return (const uint4*)(glo + u16 * 8);
}

// acc += A(hi,lo)[128xHH] x B(jt-slice)^T; B-hi from LDS, B-lo staged via LDS dbuf
__device__ __forceinline__ void gemm1024(f32x4 (*acc)[4],
                                         const unsigned short* __restrict__ ah,
                                         const unsigned short* __restrict__ al,
                                         const unsigned short* __restrict__ glo,
                                         int jt, unsigned short* lds) {
  const int tid = threadIdx.x;
  const int lane = tid & 63, wid = tid >> 6;
  const int kg = lane >> 4;
  const int r0 = wid * 32 + (lane & 15), r1 = r0 + 16;
  const unsigned short* a0h = ah + r0 * HH;
  const unsigned short* a0l = al + r0 * HH;
  const unsigned short* a1h = ah + r1 * HH;
  const unsigned short* a1l = al + r1 * HH;

  {  // stage chunk 0
    uint4 s0 = *lo_src(glo, jt, 0, tid);
    uint4 s1 = *lo_src(glo, jt, 0, tid + 256);
    *(uint4*)((char*)lds + SLO_B + tid * 16) = s0;
    *(uint4*)((char*)lds + SLO_B + 4096 + tid * 16) = s1;
  }
  __syncthreads();

  for (int c = 0; c < 16; ++c) {
    uint4 n0, n1;
    if (c < 15) {  // issue next-chunk loads early (overlap with compute)
      n0 = *lo_src(glo, jt, c + 1, tid);
      n1 = *lo_src(glo, jt, c + 1, tid + 256);
    }
#pragma unroll
    for (int kcl = 0; kcl < 2; ++kcl) {
      const int kc = c * 2 + kcl;
      const int kb = kc * 32 + kg * 8;
      const sh8 aH0 = ld8(a0h + kb), aL0 = ld8(a0l + kb);
      const sh8 aH1 = ld8(a1h + kb), aL1 = ld8(a1l + kb);
#pragma unroll
      for (int g = 0; g < 4; ++g) {
        const sh8 bH = ld8(lds + (g * 32 + kc) * 512 + lane * 8);
        const sh8 bL =
            ld8(lds + SLO_B / 2 + (c & 1) * 4096 + (g * 2 + kcl) * 512 + lane * 8);
        acc[0][g] = mfma_bf16(aH0, bH, acc[0][g]);
        acc[0][g] = mfma_bf16(aL0, bH, acc[0][g]);
        acc[0][g] = mfma_bf16(aH0, bL, acc[0][g]);
        acc[1][g] = mfma_bf16(aH1, bH, acc[1][g]);
        acc[1][g] = mfma_bf16(aL1, bH, acc[1][g]);
        acc[1][g] = mfma_bf16(aH1, bL, acc[1][g]);
      }
    }
    if (c < 15) {
      const int nb = (c + 1) & 1;
      *(uint4*)((char*)lds + SLO_B + nb * 8192 + tid * 16) = n0;
      *(uint4*)((char*)lds + SLO_B + nb * 8192 + 4096 + tid * 16) = n1;
    }
    __syncthreads();
  }
}

// encoder L0 extra: x(fp32, K=64) x Wih0; hi in LDS, lo streamed
__device__ __forceinline__ void gemm_x(f32x4 (*acc)[4], const float* __restrict__ x, int t,
                                       const unsigned short* __restrict__ wxl, int jt,
                                       const unsigned short* lds) {
  const int tid = threadIdx.x;
  const int lane = tid & 63, wid = tid >> 6;
  const int kg = lane >> 4;
  const int r0 = wid * 32 + (lane & 15), r1 = r0 + 16;
  const float* xr0 = x + (size_t)r0 * (TT * INF) + t * INF;
  const float* xr1 = x + (size_t)r1 * (TT * INF) + t * INF;
#pragma unroll
  for (int kc2 = 0; kc2 < 2; ++kc2) {
    const int kb = kc2 * 32 + kg * 8;
    sh8 xh0, xl0, xh1, xl1;
#pragma unroll
    for (int e = 0; e < 8; ++e) {
      const float v0 = xr0[kb + e];
      const unsigned short h0 = f2bf(v0);
      xh0[e] = (short)h0;
      xl0[e] = (short)f2bf(v0 - bf2f(h0));
      const float v1 = xr1[kb + e];
      const unsigned short h1 = f2bf(v1);
      xh1[e] = (short)h1;
      xl1[e] = (short)f2bf(v1 - bf2f(h1));
    }
#pragma unroll
    for (int g = 0; g < 4; ++g) {
      const sh8 bH = ld8(lds + SWX_B / 2 + (g * 2 + kc2) * 512 + lane * 8);
      const sh8 bL = ld8(wxl + (((size_t)(g * 64 + jt) * 2 + kc2) * 64 + lane) * 8);
      acc[0][g] = mfma_bf16(xh0, bH, acc[0][g]);
      acc[0][g] = mfma_bf16(xl0, bH, acc[0][g]);
      acc[0][g] = mfma_bf16(xh0, bL, acc[0][g]);
      acc[1][g] = mfma_bf16(xh1, bH, acc[1][g]);
      acc[1][g] = mfma_bf16(xl1, bH, acc[1][g]);
      acc[1][g] = mfma_bf16(xh1, bL, acc[1][g]);
    }
  }
}

__device__ __forceinline__ void store_z(f32x4 (*acc)[4], float* zb, int jt) {
  const int tid = threadIdx.x;
  const int lane = tid & 63, wid = tid >> 6;
  const int col = lane & 15, kg = lane >> 4;
#pragma unroll
  for (int m = 0; m < 2; ++m)
#pragma unroll
    for (int g = 0; g < 4; ++g) {
      const int row = g * HH + jt * 16 + col;
      const int bq = (wid * 2 + m) * 16 + kg * 4;
      *(f32x4*)(zb + (size_t)row * BB + bq) = acc[m][g];
    }
}
__device__ __forceinline__ void add_z(f32x4 (*acc)[4], const float* zb, int jt) {
  const int tid = threadIdx.x;
  const int lane = tid & 63, wid = tid >> 6;
  const int col = lane & 15, kg = lane >> 4;
#pragma unroll
  for (int m = 0; m < 2; ++m)
#pragma unroll
    for (int g = 0; g < 4; ++g) {
      const int row = g * HH + jt * 16 + col;
      const int bq = (wid * 2 + m) * 16 + kg * 4;
      acc[m][g] += *(const f32x4*)(zb + (size_t)row * BB + bq);
    }
}

// MODE: 0 plain, 1 rank-1 decoder input, 2 FC partial output
template <int MODE>
__device__ __forceinline__ void cellfin(f32x4 (*acc)[4], float (*creg)[4],
                                        const float* __restrict__ bias, int jt,
                                        unsigned short* __restrict__ nhh,
                                        unsigned short* __restrict__ nhl,
                                        const float* w0g, const float* inp_vec, float fcwj,
                                        float* fc_out) {
  const int tid = threadIdx.x;
  const int lane = tid & 63, wid = tid >> 6;
  const int col = lane & 15, kg = lane >> 4;
  const int j = jt * 16 + col;
  const float b0 = bias[j], b1 = bias[HH + j], b2 = bias[2 * HH + j], b3 = bias[3 * HH + j];
#pragma unroll
  for (int m = 0; m < 2; ++m) {
#pragma unroll
    for (int r = 0; r < 4; ++r) {
      const int b = (wid * 2 + m) * 16 + kg * 4 + r;
      float zi = acc[m][0][r] + b0;
      float zf = acc[m][1][r] + b1;
      float zg = acc[m][2][r] + b2;
      float zo = acc[m][3][r] + b3;
      if constexpr (MODE == 1) {
        const float ip = inp_vec ? inp_vec[b] : 0.f;
        zi += ip * w0g[0];
        zf += ip * w0g[1];
        zg += ip * w0g[2];
        zo += ip * w0g[3];
      }
      const float cn = sigm(zf) * creg[m][r] + sigm(zi) * tanh_f(zg);
      const float hn = sigm(zo) * tanh_f(cn);
      creg[m][r] = cn;
      const unsigned short hb = f2bf(hn);
      nhh[b * HH + j] = hb;
      nhl[b * HH + j] = f2bf(hn - bf2f(hb));
      if constexpr (MODE == 2) {
        float cb = hn * fcwj;
        cb += __shfl_xor(cb, 1);
        cb += __shfl_xor(cb, 2);
        cb += __shfl_xor(cb, 4);
        cb += __shfl_xor(cb, 8);
        if (col == 0) atomicAdd(fc_out + b, cb);
      }
    }
  }
}

__device__ __forceinline__ void zacc(f32x4 (*acc)[4]) {
#pragma unroll
  for (int m = 0; m < 2; ++m)
#pragma unroll
    for (int g = 0; g < 4; ++g) acc[m][g] = f32x4{0.f, 0.f, 0.f, 0.f};
}

__global__ __launch_bounds__(256, 1) void seq2seq_coop(KArgs a) {
  extern __shared__ unsigned short lds[];
  const int bid = blockIdx.x;
  const int role = bid >> 6;
  const int jt = bid & 63;
  const int tid = threadIdx.x;
  int bseq = 0;

  unsigned short* h0h[2] = {a.h0h0, a.h0h1};
  unsigned short* h0l[2] = {a.h0l0, a.h0l1};
  unsigned short* h1h[2] = {a.h1h0, a.h1h1};
  unsigned short* h1l[2] = {a.h1l0, a.h1l1};
  float* zb[2] = {a.zb0, a.zb1};

  if (role == 0) {
    load_whi(lds, a.whh0e_h, jt);
    load_wx(lds, a.wih0_h, jt);
  } else if (role == 1) {
    load_whi(lds, a.wih1e_h, jt);
  } else {
    load_whi(lds, a.whh1e_h, jt);
  }
  __syncthreads();

  float creg[2][4] = {};

  // ---- encoder: software-pipelined, 1 barrier per iteration ----
  for (int i = 0; i < TT + 2; ++i) {
    if (role == 0) {
      if (i < TT) {
        f32x4 acc[2][4];
        zacc(acc);
        gemm1024(acc, h0h[(i + 1) & 1], h0l[(i + 1) & 1], a.whh0e_l, jt, lds);
        gemm_x(acc, a.x, i, a.wih0_l, jt, lds);
        cellfin<0>(acc, creg, a.bias0e, jt, h0h[i & 1], h0l[i & 1], nullptr, nullptr, 0.f,
                   nullptr);
      }
    } else if (role == 1) {
      if (i >= 1 && i <= TT) {
        const int s = i - 1;
        f32x4 acc[2][4];
        zacc(acc);
        gemm1024(acc, h0h[s & 1], h0l[s & 1], a.wih1e_l, jt, lds);
        store_z(acc, zb[s & 1], jt);
      }
    } else {
      if (i >= 2) {
        const int s = i - 2;
        f32x4 acc[2][4];
        zacc(acc);
        gemm1024(acc, h1h[(s + 1) & 1], h1l[(s + 1) & 1], a.whh1e_l, jt, lds);
        add_z(acc, zb[s & 1], jt);
        cellfin<0>(acc, creg, a.bias1e, jt, h1h[s & 1], h1l[s & 1], nullptr, nullptr, 0.f,
                   nullptr);
      }
    }
    gbar(a.arrive, a.go, ++bseq, bid);
  }

  // ---- decoder: reload LDS weights, 3 phases per step ----
  if (role == 0) load_whi(lds, a.whh0d_h, jt);
  else if (role == 1) load_whi(lds, a.wih1d_h, jt);
  else load_whi(lds, a.whh1d_h, jt);
  __syncthreads();

  float w0g[4] = {0.f, 0.f, 0.f, 0.f};
  float fcwj = 0.f;
  if (role == 0) {
    const int j = jt * 16 + (tid & 15);
    w0g[0] = a.w0col[j];
    w0g[1] = a.w0col[HH + j];
    w0g[2] = a.w0col[2 * HH + j];
    w0g[3] = a.w0col[3 * HH + j];
  }
  if (role == 2) fcwj = a.fcw[jt * 16 + (tid & 15)];

  for (int s = 0; s < SS; ++s) {
    if (role == 0) {
      f32x4 acc[2][4];
      zacc(acc);
      gemm1024(acc, h0h[(s + 1) & 1], h0l[(s + 1) & 1], a.whh0d_l, jt, lds);
      cellfin<1>(acc, creg, a.bias0d, jt, h0h[s & 1], h0l[s & 1], w0g,
                 s ? a.out_tmp + (s - 1) * BB : nullptr, 0.f, nullptr);
    }
    gbar(a.arrive, a.go, ++bseq, bid);
    if (role == 1) {
      f32x4 acc[2][4];
      zacc(acc);
      gemm1024(acc, h0h[s & 1], h0l[s & 1], a.wih1d_l, jt, lds);
      store_z(acc, zb[0], jt);
    }
    gbar(a.arrive, a.go, ++bseq, bid);
    if (role == 2) {
      f32x4 acc[2][4];
      zacc(acc);
      gemm1024(acc, h1h[(s + 1) & 1], h1l[(s + 1) & 1], a.whh1d_l, jt, lds);
      add_z(acc, zb[0], jt);
      cellfin<2>(acc, creg, a.bias1d, jt, h1h[s & 1], h1l[s & 1], nullptr, nullptr, fcwj,
                 a.out_tmp + s * BB);
    }
    gbar(a.arrive, a.go, ++bseq, bid);
  }

  // ---- final: out_tmp (S,B) -> d_out (B,S) ----
  if (bid < 32) {
    const int gi = bid * 256 + tid;  // gi = b*64 + s
    const int b = gi >> 6, s2 = gi & 63;
    a.outp[gi] = a.out_tmp[s2 * BB + b];
  }
}

extern "C" void kernel_launch(void* const* d_in, const int* in_sizes, int n_in,
                              void* d_out, int out_size, void* d_ws, size_t ws_size,
                              hipStream_t stream) {
  (void)in_sizes; (void)n_in; (void)out_size; (void)ws_size;
  const float* x     = (const float*)d_in[0];
  const float* eWih0 = (const float*)d_in[1];
  const float* eWhh0 = (const float*)d_in[2];
  const float* eBih0 = (const float*)d_in[3];
  const float* eBhh0 = (const float*)d_in[4];
  const float* eWih1 = (const float*)d_in[5];
  const float* eWhh1 = (const float*)d_in[6];
  const float* eBih1 = (const float*)d_in[7];
  const float* eBhh1 = (const float*)d_in[8];
  const float* dWih0 = (const float*)d_in[9];
  const float* dWhh0 = (const float*)d_in[10];
  const float* dBih0 = (const float*)d_in[11];
  const float* dBhh0 = (const float*)d_in[12];
  const float* dWih1 = (const float*)d_in[13];
  const float* dWhh1 = (const float*)d_in[14];
  const float* dBih1 = (const float*)d_in[15];
  const float* dBhh1 = (const float*)d_in[16];
  const float* fcW   = (const float*)d_in[17];
  const float* fcB   = (const float*)d_in[18];
  float* out = (float*)d_out;

  char* base = (char*)d_ws;
  size_t off = 0;
  auto alloc = [&](size_t bytes) -> void* {
    void* p = base + off;
    off = (off + bytes + 255) & ~(size_t)255;
    return p;
  };

  // zero-initialized block (one memset): h buffers + barrier flags
  unsigned short* h0h0 = (unsigned short*)alloc(BB * HH * 2);
  unsigned short* h0h1 = (unsigned short*)alloc(BB * HH * 2);
  unsigned short* h0l0 = (unsigned short*)alloc(BB * HH * 2);
  unsigned short* h0l1 = (unsigned short*)alloc(BB * HH * 2);
  unsigned short* h1h0 = (unsigned short*)alloc(BB * HH * 2);
  unsigned short* h1h1 = (unsigned short*)alloc(BB * HH * 2);
  unsigned short* h1l0 = (unsigned short*)alloc(BB * HH * 2);
  unsigned short* h1l1 = (unsigned short*)alloc(BB * HH * 2);
  int* bar = (int*)alloc((NBLK * 16 + 16) * sizeof(int));  // arrive[192 x 64B] + go
  const size_t zbytes = off;

  float* zb0 = (float*)alloc((size_t)NG * BB * 4);
  float* zb1 = (float*)alloc((size_t)NG * BB * 4);
  float* out_tmp = (float*)alloc(SS * BB * 4);

  unsigned short* wih0_h = (unsigned short*)alloc((size_t)NG * INF * 2);
  unsigned short* wih0_l = (unsigned short*)alloc((size_t)NG * INF * 2);
  auto big = [&]() { return (unsigned short*)alloc((size_t)NG * HH * 2); };
  unsigned short *whh0e_h = big(), *whh0e_l = big();
  unsigned short *wih1e_h = big(), *wih1e_l = big();
  unsigned short *whh1e_h = big(), *whh1e_l = big();
  unsigned short *whh0d_h = big(), *whh0d_l = big();
  unsigned short *wih1d_h = big(), *wih1d_l = big();
  unsigned short *whh1d_h = big(), *whh1d_l = big();
  float* bias0e = (float*)alloc(NG * 4);
  float* bias1e = (float*)alloc(NG * 4);
  float* bias0d = (float*)alloc(NG * 4);
  float* bias1d = (float*)alloc(NG * 4);

  (void)hipMemsetAsync(base, 0, zbytes, stream);
  const int gb = (NG * HH + 255) / 256;
  prep_weight<<<gb, 256, 0, stream>>>(eWhh0, whh0e_h, whh0e_l, 10);
  prep_weight<<<gb, 256, 0, stream>>>(eWih1, wih1e_h, wih1e_l, 10);
  prep_weight<<<gb, 256, 0, stream>>>(eWhh1, whh1e_h, whh1e_l, 10);
  prep_weight<<<gb, 256, 0, stream>>>(dWhh0, whh0d_h, whh0d_l, 10);
  prep_weight<<<gb, 256, 0, stream>>>(dWih1, wih1d_h, wih1d_l, 10);
  prep_weight<<<gb, 256, 0, stream>>>(dWhh1, whh1d_h, whh1d_l, 10);
  prep_weight<<<(NG * INF + 255) / 256, 256, 0, stream>>>(eWih0, wih0_h, wih0_l, 6);
  const int gbias = (NG + 255) / 256;
  prep_bias<<<gbias, 256, 0, stream>>>(eBih0, eBhh0, bias0e);
  prep_bias<<<gbias, 256, 0, stream>>>(eBih1, eBhh1, bias1e);
  prep_bias<<<gbias, 256, 0, stream>>>(dBih0, dBhh0, bias0d);
  prep_bias<<<gbias, 256, 0, stream>>>(dBih1, dBhh1, bias1d);
  init_out<<<(SS * BB + 255) / 256, 256, 0, stream>>>(out_tmp, fcB);

  KArgs ka;
  ka.x = x;
  ka.wih0_h = wih0_h; ka.wih0_l = wih0_l;
  ka.whh0e_h = whh0e_h; ka.whh0e_l = whh0e_l;
  ka.wih1e_h = wih1e_h; ka.wih1e_l = wih1e_l;
  ka.whh1e_h = whh1e_h; ka.whh1e_l = whh1e_l;
  ka.whh0d_h = whh0d_h; ka.whh0d_l = whh0d_l;
  ka.wih1d_h = wih1d_h; ka.wih1d_l = wih1d_l;
  ka.whh1d_h = whh1d_h; ka.whh1d_l = whh1d_l;
  ka.bias0e = bias0e; ka.bias1e = bias1e; ka.bias0d = bias0d; ka.bias1d = bias1d;
  ka.w0col = dWih0; ka.fcw = fcW; ka.fcb = fcB;
  ka.h0h0 = h0h0; ka.h0h1 = h0h1; ka.h0l0 = h0l0; ka.h0l1 = h0l1;
  ka.h1h0 = h1h0; ka.h1h1 = h1h1; ka.h1l0 = h1l0; ka.h1l1 = h1l1;
  ka.zb0 = zb0; ka.zb1 = zb1;
  ka.out_tmp = out_tmp;
  ka.outp = out;
  ka.arrive = bar;
  ka.go = bar + NBLK * 16;

  (void)hipFuncSetAttribute((const void*)seq2seq_coop,
                            hipFuncAttributeMaxDynamicSharedMemorySize, LDS_BYTES);
  // Plain launch: 152KB LDS -> 1 block/CU, 192 blocks <= 256 CUs -> all
  // resident; the hand-rolled grid barrier needs no cooperative-launch API.
  seq2seq_coop<<<dim3(NBLK), dim3(256), LDS_BYTES, stream>>>(ka);
}

// Round 7
// 23567.914 us; speedup vs baseline: 2.3263x; 1.1566x over previous
//
#include <hip/hip_runtime.h>
#include <cmath>
#include <cstdint>
#include <cstddef>

#define BB   128
#define TT   512
#define INF  64
#define HH   1024
#define NG   4096
#define SS   64
#define NBLK 192
#define COORD 64   // coordinator block: role 1 (lightest), jt 0

// LDS layout (byte offsets); total 155648 B = 152 KB
#define SWHI_B 0          // hi weights: 4 gates x 32 kc x 64 lanes x 16B = 131072
#define SLO_B  131072     // lo double-buffer: 2 x 8192 B
#define SWX_B  147456     // Wih0-hi (enc L0 only): 8192 B
#define LDS_BYTES 155648

typedef __attribute__((ext_vector_type(8))) short sh8;
typedef __attribute__((ext_vector_type(4))) float f32x4;

__device__ __forceinline__ float bf2f(unsigned short u) {
  unsigned int i = ((unsigned int)u) << 16;
  return __builtin_bit_cast(float, i);
}
__device__ __forceinline__ unsigned short f2bf(float f) {
  unsigned int u = __builtin_bit_cast(unsigned int, f);
  u += 0x7FFFu + ((u >> 16) & 1u);
  return (unsigned short)(u >> 16);
}
__device__ __forceinline__ float sigm(float x) { return 1.f / (1.f + __expf(-x)); }
__device__ __forceinline__ float tanh_f(float x) {
  x = fminf(15.f, fmaxf(-15.f, x));
  const float e = __expf(2.f * x);
  return (e - 1.f) / (e + 1.f);
}
__device__ __forceinline__ sh8 ld8(const unsigned short* p) { return *(const sh8*)p; }

// Block barrier that does NOT drain vmcnt: outstanding global loads survive.
// lgkmcnt(0) makes DS writes visible; "memory" clobbers stop compiler reorder.
__device__ __forceinline__ void block_sync_lds() {
  asm volatile("s_waitcnt lgkmcnt(0)" ::: "memory");
  __builtin_amdgcn_s_barrier();
  asm volatile("" ::: "memory");
}

#if defined(__HIP_DEVICE_COMPILE__)
// Device pass: real MFMA via SFINAE shim (operand type short8 vs __bf16x8
// differs across compiler versions).
typedef __attribute__((ext_vector_type(8))) __bf16 bf8;
template <class T> T&& my_declval();
template <class V, class = void> struct mfma_takes { static constexpr bool value = false; };
template <class V>
struct mfma_takes<V, decltype((void)__builtin_amdgcn_mfma_f32_16x16x32_bf16(
                        my_declval<V>(), my_declval<V>(), my_declval<f32x4>(), 0, 0, 0))> {
  static constexpr bool value = true;
};
template <class V>
__device__ __forceinline__ f32x4 mfma_imp(V a, V b, f32x4 c) {
  return __builtin_amdgcn_mfma_f32_16x16x32_bf16(a, b, c, 0, 0, 0);
}
__device__ __forceinline__ f32x4 mfma_bf16(sh8 a, sh8 b, f32x4 c) {
  if constexpr (mfma_takes<sh8>::value) {
    return mfma_imp<sh8>(a, b, c);
  } else {
    return mfma_imp<bf8>(__builtin_bit_cast(bf8, a), __builtin_bit_cast(bf8, b), c);
  }
}
#else
// Host pass: semantic-check stub only; never codegen'd.
__device__ __forceinline__ f32x4 mfma_bf16(sh8, sh8, f32x4 c) { return c; }
#endif

// ---------- preprocessing kernels ----------
// fp32 [NG][K] row-major -> split bf16 hi/lo in MFMA B-fragment order:
// 16B-unit index = (( (n>>4)*(K/32) + (k>>5) )*64 + ((k>>3)&3)*16 + (n&15)), elem k&7.
__global__ __launch_bounds__(256) void prep_weight(const float* __restrict__ W,
                                                   unsigned short* __restrict__ hi,
                                                   unsigned short* __restrict__ lo,
                                                   int lk) {
  const int K = 1 << lk;
  const int idx = blockIdx.x * 256 + threadIdx.x;
  if (idx >= (NG << lk)) return;
  const int n = idx >> lk;
  const int k = idx & (K - 1);
  const float v = W[idx];
  const unsigned short h = f2bf(v);
  const unsigned short l = f2bf(v - bf2f(h));
  const int nkch = K >> 5;
  const size_t o =
      ((((size_t)(n >> 4) * nkch + (k >> 5)) * 64) + (((k >> 3) & 3) * 16) + (n & 15)) * 8 +
      (k & 7);
  hi[o] = h;
  lo[o] = l;
}

__global__ __launch_bounds__(256) void prep_bias(const float* __restrict__ a,
                                                 const float* __restrict__ b,
                                                 float* __restrict__ o) {
  const int i = blockIdx.x * 256 + threadIdx.x;
  if (i < NG) o[i] = a[i] + b[i];
}

__global__ __launch_bounds__(256) void init_out(float* __restrict__ out_tmp,
                                                const float* __restrict__ fcb) {
  const int i = blockIdx.x * 256 + threadIdx.x;
  if (i < SS * BB) out_tmp[i] = fcb[0];
}

// ---------- persistent kernel (manual co-residency: 152KB LDS -> 1 block/CU,
// grid 192 <= 256 CUs, so all blocks resident) ----------
struct KArgs {
  const float* x;
  const unsigned short *wih0_h, *wih0_l;
  const unsigned short *whh0e_h, *whh0e_l;
  const unsigned short *wih1e_h, *wih1e_l;
  const unsigned short *whh1e_h, *whh1e_l;
  const unsigned short *whh0d_h, *whh0d_l;
  const unsigned short *wih1d_h, *wih1d_l;
  const unsigned short *whh1d_h, *whh1d_l;
  const float *bias0e, *bias1e, *bias0d, *bias1d;
  const float *w0col, *fcw, *fcb;
  unsigned short *h0h0, *h0h1, *h0l0, *h0l1;
  unsigned short *h1h0, *h1h1, *h1l0, *h1l1;
  float *zb0, *zb1;
  float *out_tmp;
  float *outp;
  int *arrive;  // NBLK slots, stride 16 ints (64B) each
  int *go;      // 1 slot
};

// Distributed grid barrier: per-block release-store to own arrive slot (no
// RMW contention), coordinator aggregates with 192 polling threads and
// release-stores a go flag; waiters poll relaxed then one acquire load.
__device__ __forceinline__ void gbar(int* arrive, int* go, int it, int bid) {
  __syncthreads();
  const int tid = threadIdx.x;
  if (bid == COORD) {
    if (tid == 0)
      __hip_atomic_store(&arrive[COORD * 16], it, __ATOMIC_RELEASE, __HIP_MEMORY_SCOPE_AGENT);
    if (tid < NBLK) {
      while (__hip_atomic_load(&arrive[tid * 16], __ATOMIC_RELAXED, __HIP_MEMORY_SCOPE_AGENT) < it)
        __builtin_amdgcn_s_sleep(1);
    }
    __syncthreads();
    if (tid == 0) {
      __hip_atomic_store(go, it, __ATOMIC_RELEASE, __HIP_MEMORY_SCOPE_AGENT);
      (void)__hip_atomic_load(go, __ATOMIC_ACQUIRE, __HIP_MEMORY_SCOPE_AGENT);
    }
  } else {
    if (tid == 0) {
      __hip_atomic_store(&arrive[bid * 16], it, __ATOMIC_RELEASE, __HIP_MEMORY_SCOPE_AGENT);
      while (__hip_atomic_load(go, __ATOMIC_RELAXED, __HIP_MEMORY_SCOPE_AGENT) < it)
        __builtin_amdgcn_s_sleep(2);
      (void)__hip_atomic_load(go, __ATOMIC_ACQUIRE, __HIP_MEMORY_SCOPE_AGENT);
    }
  }
  __syncthreads();
}

// copy this block's hi-weight slice (4 x 32KB contiguous segments) into LDS
__device__ __forceinline__ void load_whi(unsigned short* lds, const unsigned short* hi, int jt) {
#pragma unroll
  for (int g = 0; g < 4; ++g) {
    const uint4* src = (const uint4*)(hi + ((size_t)(g * 64 + jt) * 32) * 512);
    uint4* dst = (uint4*)((char*)lds + SWHI_B + g * 32768);
    for (int u = threadIdx.x; u < 2048; u += 256) dst[u] = src[u];
  }
}
__device__ __forceinline__ void load_wx(unsigned short* lds, const unsigned short* hi, int jt) {
  for (int u = threadIdx.x; u < 512; u += 256) {
    const int g = u >> 7, rem = u & 127;
    const uint4* src = (const uint4*)(hi + ((size_t)(g * 64 + jt) * 128 + rem) * 8);
    ((uint4*)((char*)lds + SWX_B))[u] = *src;
  }
}

__device__ __forceinline__ const uint4* lo_src(const unsigned short* glo, int jt, int c, int f) {
  const int g = f >> 7, rem = f & 127, kcl = rem >> 6, l = rem & 63;
  const size_t u16 = ((size_t)((g * 64 + jt) * 32) + c * 2 + kcl) * 64 + l;
  return (const uint4*)(glo + u16 * 8);
}

__device__ __forceinline__ void stlo(unsigned short* lds, int b, int tid, uint4 A, uint4 B) {
  *(uint4*)((char*)lds + SLO_B + b * 8192 + tid * 16) = A;
  *(uint4*)((char*)lds + SLO_B + b * 8192 + 4096 + tid * 16) = B;
}

// load A fragments (hi+lo, 2 rows) for K-chunk c into named regs (static idx)
__device__ __forceinline__ void lda(sh8 (&H0)[2], sh8 (&L0)[2], sh8 (&H1)[2], sh8 (&L1)[2],
                                    const unsigned short* a0h, const unsigned short* a0l,
                                    const unsigned short* a1h, const unsigned short* a1l,
                                    int c, int kg) {
#pragma unroll
  for (int kcl = 0; kcl < 2; ++kcl) {
    const int kb = c * 64 + kcl * 32 + kg * 8;
    H0[kcl] = ld8(a0h + kb);
    L0[kcl] = ld8(a0l + kb);
    H1[kcl] = ld8(a1h + kb);
    L1[kcl] = ld8(a1l + kb);
  }
}

// 48 MFMAs of one K-chunk: B-hi from LDS-resident region, B-lo from stage buf b
__device__ __forceinline__ void compute_chunk(f32x4 (*acc)[4], const unsigned short* lds,
                                              int c, int b, int lane, const sh8 (&H0)[2],
                                              const sh8 (&L0)[2], const sh8 (&H1)[2],
                                              const sh8 (&L1)[2]) {
#pragma unroll
  for (int kcl = 0; kcl < 2; ++kcl) {
    const int kc = c * 2 + kcl;
#pragma unroll
    for (int g = 0; g < 4; ++g) {
      const sh8 bH = ld8(lds + (g * 32 + kc) * 512 + lane * 8);
      const sh8 bL = ld8(lds + SLO_B / 2 + b * 4096 + (g * 2 + kcl) * 512 + lane * 8);
      acc[0][g] = mfma_bf16(H0[kcl], bH, acc[0][g]);
      acc[0][g] = mfma_bf16(L0[kcl], bH, acc[0][g]);
      acc[0][g] = mfma_bf16(H0[kcl], bL, acc[0][g]);
      acc[1][g] = mfma_bf16(H1[kcl], bH, acc[1][g]);
      acc[1][g] = mfma_bf16(L1[kcl], bH, acc[1][g]);
      acc[1][g] = mfma_bf16(H1[kcl], bL, acc[1][g]);
    }
  }
}

// acc += A(hi,lo)[128xHH] x B(jt-slice)^T. Pipelined: lo-stage loads issued 2
// chunks ahead (regs->LDS dbuf), A-frags 1 chunk ahead; barriers do not drain
// vmcnt (block_sync_lds) so prefetches stay in flight across chunk syncs.
__device__ __forceinline__ void gemm1024(f32x4 (*acc)[4],
                                         const unsigned short* __restrict__ ah,
                                         const unsigned short* __restrict__ al,
                                         const unsigned short* __restrict__ glo,
                                         int jt, unsigned short* lds) {
  const int tid = threadIdx.x;
  const int lane = tid & 63, wid = tid >> 6;
  const int kg = lane >> 4;
  const int r0 = wid * 32 + (lane & 15), r1 = r0 + 16;
  const unsigned short* a0h = ah + r0 * HH;
  const unsigned short* a0l = al + r0 * HH;
  const unsigned short* a1h = ah + r1 * HH;
  const unsigned short* a1l = al + r1 * HH;

  sh8 cH0[2], cL0[2], cH1[2], cL1[2];
  sh8 nH0[2], nL0[2], nH1[2], nL1[2];
  uint4 pA = *lo_src(glo, jt, 0, tid), pB = *lo_src(glo, jt, 0, tid + 256);
  uint4 qA = *lo_src(glo, jt, 1, tid), qB = *lo_src(glo, jt, 1, tid + 256);
  lda(cH0, cL0, cH1, cL1, a0h, a0l, a1h, a1l, 0, kg);
  stlo(lds, 0, tid, pA, pB);
  block_sync_lds();

#pragma unroll 1
  for (int cc = 0; cc < 16; cc += 2) {
    // ---- even chunk cc: stage buf 0, A regs c* ----
    if (cc + 2 < 16) {
      pA = *lo_src(glo, jt, cc + 2, tid);
      pB = *lo_src(glo, jt, cc + 2, tid + 256);
    }
    lda(nH0, nL0, nH1, nL1, a0h, a0l, a1h, a1l, cc + 1, kg);
    compute_chunk(acc, lds, cc, 0, lane, cH0, cL0, cH1, cL1);
    stlo(lds, 1, tid, qA, qB);
    block_sync_lds();
    // ---- odd chunk cc+1: stage buf 1, A regs n* ----
    if (cc + 3 < 16) {
      qA = *lo_src(glo, jt, cc + 3, tid);
      qB = *lo_src(glo, jt, cc + 3, tid + 256);
    }
    if (cc + 2 < 16) lda(cH0, cL0, cH1, cL1, a0h, a0l, a1h, a1l, cc + 2, kg);
    compute_chunk(acc, lds, cc + 1, 1, lane, nH0, nL0, nH1, nL1);
    if (cc + 2 < 16) {
      stlo(lds, 0, tid, pA, pB);
      block_sync_lds();
    }
  }
}

// encoder L0 extra: x(fp32, K=64) x Wih0; hi in LDS, lo streamed
__device__ __forceinline__ void gemm_x(f32x4 (*acc)[4], const float* __restrict__ x, int t,
                                       const unsigned short* __restrict__ wxl, int jt,
                                       const unsigned short* lds) {
  const int tid = threadIdx.x;
  const int lane = tid & 63, wid = tid >> 6;
  const int kg = lane >> 4;
  const int r0 = wid * 32 + (lane & 15), r1 = r0 + 16;
  const float* xr0 = x + (size_t)r0 * (TT * INF) + t * INF;
  const float* xr1 = x + (size_t)r1 * (TT * INF) + t * INF;
#pragma unroll
  for (int kc2 = 0; kc2 < 2; ++kc2) {
    const int kb = kc2 * 32 + kg * 8;
    sh8 xh0, xl0, xh1, xl1;
#pragma unroll
    for (int e = 0; e < 8; ++e) {
      const float v0 = xr0[kb + e];
      const unsigned short h0 = f2bf(v0);
      xh0[e] = (short)h0;
      xl0[e] = (short)f2bf(v0 - bf2f(h0));
      const float v1 = xr1[kb + e];
      const unsigned short h1 = f2bf(v1);
      xh1[e] = (short)h1;
      xl1[e] = (short)f2bf(v1 - bf2f(h1));
    }
#pragma unroll
    for (int g = 0; g < 4; ++g) {
      const sh8 bH = ld8(lds + SWX_B / 2 + (g * 2 + kc2) * 512 + lane * 8);
      const sh8 bL = ld8(wxl + (((size_t)(g * 64 + jt) * 2 + kc2) * 64 + lane) * 8);
      acc[0][g] = mfma_bf16(xh0, bH, acc[0][g]);
      acc[0][g] = mfma_bf16(xl0, bH, acc[0][g]);
      acc[0][g] = mfma_bf16(xh0, bL, acc[0][g]);
      acc[1][g] = mfma_bf16(xh1, bH, acc[1][g]);
      acc[1][g] = mfma_bf16(xl1, bH, acc[1][g]);
      acc[1][g] = mfma_bf16(xh1, bL, acc[1][g]);
    }
  }
}

__device__ __forceinline__ void store_z(f32x4 (*acc)[4], float* zb, int jt) {
  const int tid = threadIdx.x;
  const int lane = tid & 63, wid = tid >> 6;
  const int col = lane & 15, kg = lane >> 4;
#pragma unroll
  for (int m = 0; m < 2; ++m)
#pragma unroll
    for (int g = 0; g < 4; ++g) {
      const int row = g * HH + jt * 16 + col;
      const int bq = (wid * 2 + m) * 16 + kg * 4;
      *(f32x4*)(zb + (size_t)row * BB + bq) = acc[m][g];
    }
}
__device__ __forceinline__ void add_z(f32x4 (*acc)[4], const float* zb, int jt) {
  const int tid = threadIdx.x;
  const int lane = tid & 63, wid = tid >> 6;
  const int col = lane & 15, kg = lane >> 4;
#pragma unroll
  for (int m = 0; m < 2; ++m)
#pragma unroll
    for (int g = 0; g < 4; ++g) {
      const int row = g * HH + jt * 16 + col;
      const int bq = (wid * 2 + m) * 16 + kg * 4;
      acc[m][g] += *(const f32x4*)(zb + (size_t)row * BB + bq);
    }
}

// MODE: 0 plain, 1 rank-1 decoder input, 2 FC partial output
template <int MODE>
__device__ __forceinline__ void cellfin(f32x4 (*acc)[4], float (*creg)[4],
                                        const float* __restrict__ bias, int jt,
                                        unsigned short* __restrict__ nhh,
                                        unsigned short* __restrict__ nhl,
                                        const float* w0g, const float* inp_vec, float fcwj,
                                        float* fc_out) {
  const int tid = threadIdx.x;
  const int lane = tid & 63, wid = tid >> 6;
  const int col = lane & 15, kg = lane >> 4;
  const int j = jt * 16 + col;
  const float b0 = bias[j], b1 = bias[HH + j], b2 = bias[2 * HH + j], b3 = bias[3 * HH + j];
#pragma unroll
  for (int m = 0; m < 2; ++m) {
#pragma unroll
    for (int r = 0; r < 4; ++r) {
      const int b = (wid * 2 + m) * 16 + kg * 4 + r;
      float zi = acc[m][0][r] + b0;
      float zf = acc[m][1][r] + b1;
      float zg = acc[m][2][r] + b2;
      float zo = acc[m][3][r] + b3;
      if constexpr (MODE == 1) {
        const float ip = inp_vec ? inp_vec[b] : 0.f;
        zi += ip * w0g[0];
        zf += ip * w0g[1];
        zg += ip * w0g[2];
        zo += ip * w0g[3];
      }
      const float cn = sigm(zf) * creg[m][r] + sigm(zi) * tanh_f(zg);
      const float hn = sigm(zo) * tanh_f(cn);
      creg[m][r] = cn;
      const unsigned short hb = f2bf(hn);
      nhh[b * HH + j] = hb;
      nhl[b * HH + j] = f2bf(hn - bf2f(hb));
      if constexpr (MODE == 2) {
        float cb = hn * fcwj;
        cb += __shfl_xor(cb, 1);
        cb += __shfl_xor(cb, 2);
        cb += __shfl_xor(cb, 4);
        cb += __shfl_xor(cb, 8);
        if (col == 0) atomicAdd(fc_out + b, cb);
      }
    }
  }
}

__device__ __forceinline__ void zacc(f32x4 (*acc)[4]) {
#pragma unroll
  for (int m = 0; m < 2; ++m)
#pragma unroll
    for (int g = 0; g < 4; ++g) acc[m][g] = f32x4{0.f, 0.f, 0.f, 0.f};
}

__global__ __launch_bounds__(256, 1) void seq2seq_coop(KArgs a) {
  extern __shared__ unsigned short lds[];
  const int bid = blockIdx.x;
  const int role = bid >> 6;
  const int jt = bid & 63;
  const int tid = threadIdx.x;
  int bseq = 0;

  unsigned short* h0h[2] = {a.h0h0, a.h0h1};
  unsigned short* h0l[2] = {a.h0l0, a.h0l1};
  unsigned short* h1h[2] = {a.h1h0, a.h1h1};
  unsigned short* h1l[2] = {a.h1l0, a.h1l1};
  float* zb[2] = {a.zb0, a.zb1};

  if (role == 0) {
    load_whi(lds, a.whh0e_h, jt);
    load_wx(lds, a.wih0_h, jt);
  } else if (role == 1) {
    load_whi(lds, a.wih1e_h, jt);
  } else {
    load_whi(lds, a.whh1e_h, jt);
  }
  __syncthreads();

  float creg[2][4] = {};

  // ---- encoder: software-pipelined, 1 barrier per iteration ----
  for (int i = 0; i < TT + 2; ++i) {
    if (role == 0) {
      if (i < TT) {
        f32x4 acc[2][4];
        zacc(acc);
        gemm1024(acc, h0h[(i + 1) & 1], h0l[(i + 1) & 1], a.whh0e_l, jt, lds);
        gemm_x(acc, a.x, i, a.wih0_l, jt, lds);
        cellfin<0>(acc, creg, a.bias0e, jt, h0h[i & 1], h0l[i & 1], nullptr, nullptr, 0.f,
                   nullptr);
      }
    } else if (role == 1) {
      if (i >= 1 && i <= TT) {
        const int s = i - 1;
        f32x4 acc[2][4];
        zacc(acc);
        gemm1024(acc, h0h[s & 1], h0l[s & 1], a.wih1e_l, jt, lds);
        store_z(acc, zb[s & 1], jt);
      }
    } else {
      if (i >= 2) {
        const int s = i - 2;
        f32x4 acc[2][4];
        zacc(acc);
        gemm1024(acc, h1h[(s + 1) & 1], h1l[(s + 1) & 1], a.whh1e_l, jt, lds);
        add_z(acc, zb[s & 1], jt);
        cellfin<0>(acc, creg, a.bias1e, jt, h1h[s & 1], h1l[s & 1], nullptr, nullptr, 0.f,
                   nullptr);
      }
    }
    gbar(a.arrive, a.go, ++bseq, bid);
  }

  // ---- decoder: reload LDS weights ----
  if (role == 0) load_whi(lds, a.whh0d_h, jt);
  else if (role == 1) load_whi(lds, a.wih1d_h, jt);
  else load_whi(lds, a.whh1d_h, jt);
  __syncthreads();

  float w0g[4] = {0.f, 0.f, 0.f, 0.f};
  float fcwj = 0.f;
  if (role == 0) {
    const int j = jt * 16 + (tid & 15);
    w0g[0] = a.w0col[j];
    w0g[1] = a.w0col[HH + j];
    w0g[2] = a.w0col[2 * HH + j];
    w0g[3] = a.w0col[3 * HH + j];
  }
  if (role == 2) fcwj = a.fcw[jt * 16 + (tid & 15)];

  // Decoder schedule per step s:
  //  phase A: role0 cell0 (gemm+fin); role2 Whh1 x h1[s] gemm (acc held in regs)
  //  phase B: role1 Wih1 x h0[s+1] gemm -> zb
  //  phase C: role2 add_z + cellfin + FC partial (cheap)
  for (int s = 0; s < SS; ++s) {
    f32x4 acc2[2][4];
    if (role == 2) {
      zacc(acc2);
      gemm1024(acc2, h1h[(s + 1) & 1], h1l[(s + 1) & 1], a.whh1d_l, jt, lds);
    }
    if (role == 0) {
      f32x4 acc[2][4];
      zacc(acc);
      gemm1024(acc, h0h[(s + 1) & 1], h0l[(s + 1) & 1], a.whh0d_l, jt, lds);
      cellfin<1>(acc, creg, a.bias0d, jt, h0h[s & 1], h0l[s & 1], w0g,
                 s ? a.out_tmp + (s - 1) * BB : nullptr, 0.f, nullptr);
    }
    gbar(a.arrive, a.go, ++bseq, bid);
    if (role == 1) {
      f32x4 acc[2][4];
      zacc(acc);
      gemm1024(acc, h0h[s & 1], h0l[s & 1], a.wih1d_l, jt, lds);
      store_z(acc, zb[0], jt);
    }
    gbar(a.arrive, a.go, ++bseq, bid);
    if (role == 2) {
      add_z(acc2, zb[0], jt);
      cellfin<2>(acc2, creg, a.bias1d, jt, h1h[s & 1], h1l[s & 1], nullptr, nullptr, fcwj,
                 a.out_tmp + s * BB);
    }
    gbar(a.arrive, a.go, ++bseq, bid);
  }

  // ---- final: out_tmp (S,B) -> d_out (B,S) ----
  if (bid < 32) {
    const int gi = bid * 256 + tid;  // gi = b*64 + s
    const int b = gi >> 6, s2 = gi & 63;
    a.outp[gi] = a.out_tmp[s2 * BB + b];
  }
}

extern "C" void kernel_launch(void* const* d_in, const int* in_sizes, int n_in,
                              void* d_out, int out_size, void* d_ws, size_t ws_size,
                              hipStream_t stream) {
  (void)in_sizes; (void)n_in; (void)out_size; (void)ws_size;
  const float* x     = (const float*)d_in[0];
  const float* eWih0 = (const float*)d_in[1];
  const float* eWhh0 = (const float*)d_in[2];
  const float* eBih0 = (const float*)d_in[3];
  const float* eBhh0 = (const float*)d_in[4];
  const float* eWih1 = (const float*)d_in[5];
  const float* eWhh1 = (const float*)d_in[6];
  const float* eBih1 = (const float*)d_in[7];
  const float* eBhh1 = (const float*)d_in[8];
  const float* dWih0 = (const float*)d_in[9];
  const float* dWhh0 = (const float*)d_in[10];
  const float* dBih0 = (const float*)d_in[11];
  const float* dBhh0 = (const float*)d_in[12];
  const float* dWih1 = (const float*)d_in[13];
  const float* dWhh1 = (const float*)d_in[14];
  const float* dBih1 = (const float*)d_in[15];
  const float* dBhh1 = (const float*)d_in[16];
  const float* fcW   = (const float*)d_in[17];
  const float* fcB   = (const float*)d_in[18];
  float* out = (float*)d_out;

  char* base = (char*)d_ws;
  size_t off = 0;
  auto alloc = [&](size_t bytes) -> void* {
    void* p = base + off;
    off = (off + bytes + 255) & ~(size_t)255;
    return p;
  };

  // zero-initialized block (one memset): h buffers + barrier flags
  unsigned short* h0h0 = (unsigned short*)alloc(BB * HH * 2);
  unsigned short* h0h1 = (unsigned short*)alloc(BB * HH * 2);
  unsigned short* h0l0 = (unsigned short*)alloc(BB * HH * 2);
  unsigned short* h0l1 = (unsigned short*)alloc(BB * HH * 2);
  unsigned short* h1h0 = (unsigned short*)alloc(BB * HH * 2);
  unsigned short* h1h1 = (unsigned short*)alloc(BB * HH * 2);
  unsigned short* h1l0 = (unsigned short*)alloc(BB * HH * 2);
  unsigned short* h1l1 = (unsigned short*)alloc(BB * HH * 2);
  int* bar = (int*)alloc((NBLK * 16 + 16) * sizeof(int));  // arrive[192 x 64B] + go
  const size_t zbytes = off;

  float* zb0 = (float*)alloc((size_t)NG * BB * 4);
  float* zb1 = (float*)alloc((size_t)NG * BB * 4);
  float* out_tmp = (float*)alloc(SS * BB * 4);

  unsigned short* wih0_h = (unsigned short*)alloc((size_t)NG * INF * 2);
  unsigned short* wih0_l = (unsigned short*)alloc((size_t)NG * INF * 2);
  auto big = [&]() { return (unsigned short*)alloc((size_t)NG * HH * 2); };
  unsigned short *whh0e_h = big(), *whh0e_l = big();
  unsigned short *wih1e_h = big(), *wih1e_l = big();
  unsigned short *whh1e_h = big(), *whh1e_l = big();
  unsigned short *whh0d_h = big(), *whh0d_l = big();
  unsigned short *wih1d_h = big(), *wih1d_l = big();
  unsigned short *whh1d_h = big(), *whh1d_l = big();
  float* bias0e = (float*)alloc(NG * 4);
  float* bias1e = (float*)alloc(NG * 4);
  float* bias0d = (float*)alloc(NG * 4);
  float* bias1d = (float*)alloc(NG * 4);

  (void)hipMemsetAsync(base, 0, zbytes, stream);
  const int gb = (NG * HH + 255) / 256;
  prep_weight<<<gb, 256, 0, stream>>>(eWhh0, whh0e_h, whh0e_l, 10);
  prep_weight<<<gb, 256, 0, stream>>>(eWih1, wih1e_h, wih1e_l, 10);
  prep_weight<<<gb, 256, 0, stream>>>(eWhh1, whh1e_h, whh1e_l, 10);
  prep_weight<<<gb, 256, 0, stream>>>(dWhh0, whh0d_h, whh0d_l, 10);
  prep_weight<<<gb, 256, 0, stream>>>(dWih1, wih1d_h, wih1d_l, 10);
  prep_weight<<<gb, 256, 0, stream>>>(dWhh1, whh1d_h, whh1d_l, 10);
  prep_weight<<<(NG * INF + 255) / 256, 256, 0, stream>>>(eWih0, wih0_h, wih0_l, 6);
  const int gbias = (NG + 255) / 256;
  prep_bias<<<gbias, 256, 0, stream>>>(eBih0, eBhh0, bias0e);
  prep_bias<<<gbias, 256, 0, stream>>>(eBih1, eBhh1, bias1e);
  prep_bias<<<gbias, 256, 0, stream>>>(dBih0, dBhh0, bias0d);
  prep_bias<<<gbias, 256, 0, stream>>>(dBih1, dBhh1, bias1d);
  init_out<<<(SS * BB + 255) / 256, 256, 0, stream>>>(out_tmp, fcB);

  KArgs ka;
  ka.x = x;
  ka.wih0_h = wih0_h; ka.wih0_l = wih0_l;
  ka.whh0e_h = whh0e_h; ka.whh0e_l = whh0e_l;
  ka.wih1e_h = wih1e_h; ka.wih1e_l = wih1e_l;
  ka.whh1e_h = whh1e_h; ka.whh1e_l = whh1e_l;
  ka.whh0d_h = whh0d_h; ka.whh0d_l = whh0d_l;
  ka.wih1d_h = wih1d_h; ka.wih1d_l = wih1d_l;
  ka.whh1d_h = whh1d_h; ka.whh1d_l = whh1d_l;
  ka.bias0e = bias0e; ka.bias1e = bias1e; ka.bias0d = bias0d; ka.bias1d = bias1d;
  ka.w0col = dWih0; ka.fcw = fcW; ka.fcb = fcB;
  ka.h0h0 = h0h0; ka.h0h1 = h0h1; ka.h0l0 = h0l0; ka.h0l1 = h0l1;
  ka.h1h0 = h1h0; ka.h1h1 = h1h1; ka.h1l0 = h1l0; ka.h1l1 = h1l1;
  ka.zb0 = zb0; ka.zb1 = zb1;
  ka.out_tmp = out_tmp;
  ka.outp = out;
  ka.arrive = bar;
  ka.go = bar + NBLK * 16;

  (void)hipFuncSetAttribute((const void*)seq2seq_coop,
                            hipFuncAttributeMaxDynamicSharedMemorySize, LDS_BYTES);
  seq2seq_coop<<<dim3(NBLK), dim3(256), LDS_BYTES, stream>>>(ka);
}

// Round 9
// 15617.435 us; speedup vs baseline: 3.5106x; 1.5091x over previous
//
#include <hip/hip_runtime.h>
#include <cmath>
#include <cstdint>
#include <cstddef>

#define BB   128
#define TT   512
#define INF  64
#define HH   1024
#define NG   4096
#define SS   64
#define NBLK 192
#define COORD 64   // coordinator block: role 1 (lightest), jt 0
#define NTHR 512   // 8 waves

// LDS layout (byte offsets); total 155648 B = 152 KB
#define SWHI_B 0          // hi weights: 4 gates x 32 kc x 64 lanes x 16B = 131072
#define SLO_B  131072     // lo double-buffer: 2 x 8192 B
#define SWX_B  147456     // Wih0-hi (enc L0 only): 8192 B
#define LDS_BYTES 155648

typedef __attribute__((ext_vector_type(8))) short sh8;
typedef __attribute__((ext_vector_type(4))) float f32x4;

__device__ __forceinline__ float bf2f(unsigned short u) {
  unsigned int i = ((unsigned int)u) << 16;
  return __builtin_bit_cast(float, i);
}
__device__ __forceinline__ unsigned short f2bf(float f) {
  unsigned int u = __builtin_bit_cast(unsigned int, f);
  u += 0x7FFFu + ((u >> 16) & 1u);
  return (unsigned short)(u >> 16);
}
__device__ __forceinline__ float sigm(float x) { return 1.f / (1.f + __expf(-x)); }
__device__ __forceinline__ float tanh_f(float x) {
  x = fminf(15.f, fmaxf(-15.f, x));
  const float e = __expf(2.f * x);
  return (e - 1.f) / (e + 1.f);
}
__device__ __forceinline__ sh8 ld8(const unsigned short* p) { return *(const sh8*)p; }

// ---- coherent (L1+L2-bypass) accessors for cross-block mutable data ----
__device__ __forceinline__ void ld8sc(sh8& d, const unsigned short* p) {
  asm volatile("global_load_dwordx4 %0, %1, off sc0 sc1" : "=v"(d) : "v"(p));
}
__device__ __forceinline__ void ldlo(uint4& d, const uint4* p) {  // cached (weights)
  asm volatile("global_load_dwordx4 %0, %1, off" : "=v"(d) : "v"(p));
}
__device__ __forceinline__ void ldx4sc(f32x4& d, const float* p) {
  asm volatile("global_load_dwordx4 %0, %1, off sc0 sc1" : "=v"(d) : "v"(p));
}
__device__ __forceinline__ void stx4sc(float* p, f32x4 v) {
  asm volatile("global_store_dwordx4 %0, %1, off sc0 sc1" :: "v"(p), "v"(v) : "memory");
}
__device__ __forceinline__ void st16sc(unsigned short* p, unsigned int v) {
  asm volatile("global_store_short %0, %1, off sc0 sc1" :: "v"(p), "v"(v) : "memory");
}
// counted waits (rule #18: sched_barrier(0) right after stops MFMA hoisting)
__device__ __forceinline__ void waitv(int n) {
  if (n == 0)
    asm volatile("s_waitcnt vmcnt(0)" ::: "memory");
  else
    asm volatile("s_waitcnt vmcnt(5)" ::: "memory");
  __builtin_amdgcn_sched_barrier(0);
}

// Block barrier that does NOT drain vmcnt.
__device__ __forceinline__ void block_sync_lds() {
  asm volatile("s_waitcnt lgkmcnt(0)" ::: "memory");
  __builtin_amdgcn_s_barrier();
  asm volatile("" ::: "memory");
}

#if defined(__HIP_DEVICE_COMPILE__)
typedef __attribute__((ext_vector_type(8))) __bf16 bf8;
template <class T> T&& my_declval();
template <class V, class = void> struct mfma_takes { static constexpr bool value = false; };
template <class V>
struct mfma_takes<V, decltype((void)__builtin_amdgcn_mfma_f32_16x16x32_bf16(
                        my_declval<V>(), my_declval<V>(), my_declval<f32x4>(), 0, 0, 0))> {
  static constexpr bool value = true;
};
template <class V>
__device__ __forceinline__ f32x4 mfma_imp(V a, V b, f32x4 c) {
  return __builtin_amdgcn_mfma_f32_16x16x32_bf16(a, b, c, 0, 0, 0);
}
__device__ __forceinline__ f32x4 mfma_bf16(sh8 a, sh8 b, f32x4 c) {
  if constexpr (mfma_takes<sh8>::value) {
    return mfma_imp<sh8>(a, b, c);
  } else {
    return mfma_imp<bf8>(__builtin_bit_cast(bf8, a), __builtin_bit_cast(bf8, b), c);
  }
}
#else
__device__ __forceinline__ f32x4 mfma_bf16(sh8, sh8, f32x4 c) { return c; }
#endif

// ---------- preprocessing ----------
__global__ __launch_bounds__(256) void prep_weight(const float* __restrict__ W,
                                                   unsigned short* __restrict__ hi,
                                                   unsigned short* __restrict__ lo,
                                                   int lk) {
  const int K = 1 << lk;
  const int idx = blockIdx.x * 256 + threadIdx.x;
  if (idx >= (NG << lk)) return;
  const int n = idx >> lk;
  const int k = idx & (K - 1);
  const float v = W[idx];
  const unsigned short h = f2bf(v);
  const unsigned short l = f2bf(v - bf2f(h));
  const int nkch = K >> 5;
  const size_t o =
      ((((size_t)(n >> 4) * nkch + (k >> 5)) * 64) + (((k >> 3) & 3) * 16) + (n & 15)) * 8 +
      (k & 7);
  hi[o] = h;
  lo[o] = l;
}

__global__ __launch_bounds__(256) void prep_bias(const float* __restrict__ a,
                                                 const float* __restrict__ b,
                                                 float* __restrict__ o) {
  const int i = blockIdx.x * 256 + threadIdx.x;
  if (i < NG) o[i] = a[i] + b[i];
}

__global__ __launch_bounds__(256) void init_out(float* __restrict__ out_tmp,
                                                const float* __restrict__ fcb) {
  const int i = blockIdx.x * 256 + threadIdx.x;
  if (i < SS * BB) out_tmp[i] = fcb[0];
}

// ---------- persistent kernel ----------
struct KArgs {
  const float* x;
  const unsigned short *wih0_h, *wih0_l;
  const unsigned short *whh0e_h, *whh0e_l;
  const unsigned short *wih1e_h, *wih1e_l;
  const unsigned short *whh1e_h, *whh1e_l;
  const unsigned short *whh0d_h, *whh0d_l;
  const unsigned short *wih1d_h, *wih1d_l;
  const unsigned short *whh1d_h, *whh1d_l;
  const float *bias0e, *bias1e, *bias0d, *bias1d;
  const float *w0col, *fcw, *fcb;
  unsigned short *h0h0, *h0h1, *h0l0, *h0l1;
  unsigned short *h1h0, *h1h1, *h1l0, *h1l1;
  float *zb0, *zb1;
  float *out_tmp;
  float *outp;
  int *arrive;  // NBLK slots, 64B apart
  int *go;
};

// Fully-relaxed grid barrier. Mutable data travels via sc0/sc1 ops (L2-bypass,
// visible at coherence point once vmcnt retires); flags are relaxed agent
// atomics (also sc1). Explicit vmcnt(0) drains each wave's asm stores (the
// compiler can't see them) before its arrive. NO acquire/release anywhere ->
// no L2 invalidation -> cached weights stay L2-warm across all iterations.
__device__ __forceinline__ void gbar(int* arrive, int* go, int it, int bid) {
  asm volatile("s_waitcnt vmcnt(0)" ::: "memory");
  __syncthreads();
  const int tid = threadIdx.x;
  if (bid == COORD) {
    if (tid == 0)
      __hip_atomic_store(&arrive[COORD * 16], it, __ATOMIC_RELAXED, __HIP_MEMORY_SCOPE_AGENT);
    if (tid < NBLK) {
      while (__hip_atomic_load(&arrive[tid * 16], __ATOMIC_RELAXED, __HIP_MEMORY_SCOPE_AGENT) < it)
        __builtin_amdgcn_s_sleep(1);
    }
    __syncthreads();
    if (tid == 0)
      __hip_atomic_store(go, it, __ATOMIC_RELAXED, __HIP_MEMORY_SCOPE_AGENT);
  } else {
    if (tid == 0) {
      __hip_atomic_store(&arrive[bid * 16], it, __ATOMIC_RELAXED, __HIP_MEMORY_SCOPE_AGENT);
      while (__hip_atomic_load(go, __ATOMIC_RELAXED, __HIP_MEMORY_SCOPE_AGENT) < it)
        __builtin_amdgcn_s_sleep(2);
    }
  }
  __syncthreads();
  asm volatile("" ::: "memory");
}

// hi-weight slice (4 x 32KB contiguous) -> LDS (cached loads; read-only data)
__device__ __forceinline__ void load_whi(unsigned short* lds, const unsigned short* hi, int jt) {
#pragma unroll
  for (int g = 0; g < 4; ++g) {
    const uint4* src = (const uint4*)(hi + ((size_t)(g * 64 + jt) * 32) * 512);
    uint4* dst = (uint4*)((char*)lds + SWHI_B + g * 32768);
    for (int u = threadIdx.x; u < 2048; u += NTHR) dst[u] = src[u];
  }
}
__device__ __forceinline__ void load_wx(unsigned short* lds, const unsigned short* hi, int jt) {
  const int u = threadIdx.x;  // 512 units of 16B
  const int g = u >> 7, rem = u & 127;
  const uint4* src = (const uint4*)(hi + ((size_t)(g * 64 + jt) * 128 + rem) * 8);
  ((uint4*)((char*)lds + SWX_B))[u] = *src;
}

__device__ __forceinline__ const uint4* lo_src(const unsigned short* glo, int jt, int c, int f) {
  const int g = f >> 7, rem = f & 127, kcl = rem >> 6, l = rem & 63;
  const size_t u16 = ((size_t)((g * 64 + jt) * 32) + c * 2 + kcl) * 64 + l;
  return (const uint4*)(glo + u16 * 8);
}
__device__ __forceinline__ void stlo(unsigned short* lds, int buf, int tid, uint4 q) {
  *(uint4*)((char*)lds + SLO_B + buf * 8192 + tid * 16) = q;
}

// one K-chunk: 24 MFMA per wave (1 m-tile of 16 rows per wave, 8 waves = 128)
__device__ __forceinline__ void compute_chunk(f32x4* acc, const unsigned short* lds,
                                              int c, int buf, int lane,
                                              const sh8 (&H)[2], const sh8 (&L)[2]) {
#pragma unroll
  for (int kcl = 0; kcl < 2; ++kcl) {
    const int kc = c * 2 + kcl;
#pragma unroll
    for (int g = 0; g < 4; ++g) {
      const sh8 bH = ld8(lds + (g * 32 + kc) * 512 + lane * 8);
      const sh8 bL = ld8(lds + SLO_B / 2 + buf * 4096 + (g * 2 + kcl) * 512 + lane * 8);
      acc[g] = mfma_bf16(H[kcl], bH, acc[g]);
      acc[g] = mfma_bf16(L[kcl], bH, acc[g]);
      acc[g] = mfma_bf16(H[kcl], bL, acc[g]);
    }
  }
}

// acc += A(hi,lo)[128xHH] x B(jt-slice)^T. A via sc0/sc1 (coherent), lo via
// cached loads (L2-warm). 2-chunk-ahead issue, counted vmcnt, full unroll.
// Entry vmcnt(0) establishes a clean baseline so counted waits are exact
// (inside the loop the ONLY vmcnt ops are this function's asm loads).
__device__ __forceinline__ void gemm1024(f32x4* acc,
                                         const unsigned short* __restrict__ ah,
                                         const unsigned short* __restrict__ al,
                                         const unsigned short* __restrict__ glo,
                                         int jt, unsigned short* lds) {
  const int tid = threadIdx.x;
  const int lane = tid & 63, wid = tid >> 6;
  const int kg = lane >> 4;
  const int arow = wid * 16 + (lane & 15);
  const unsigned short* arh = ah + (size_t)arow * HH;
  const unsigned short* arl = al + (size_t)arow * HH;

  sh8 AH[3][2], AL[3][2];
  uint4 LOQ[3];

  asm volatile("s_waitcnt vmcnt(0)" ::: "memory");  // clean vmcnt baseline
#pragma unroll
  for (int p = 0; p < 2; ++p) {  // issue chunks 0,1 (5 loads each)
#pragma unroll
    for (int kcl = 0; kcl < 2; ++kcl) {
      ld8sc(AH[p][kcl], arh + p * 64 + kcl * 32 + kg * 8);
      ld8sc(AL[p][kcl], arl + p * 64 + kcl * 32 + kg * 8);
    }
    ldlo(LOQ[p], lo_src(glo, jt, p, tid));
  }
  waitv(5);  // chunk 0's 5 loads done (chunk 1's 5 still in flight)
  stlo(lds, 0, tid, LOQ[0]);
  block_sync_lds();

#pragma unroll
  for (int c = 0; c < 16; ++c) {
    const int s0 = c % 3, s1 = (c + 1) % 3, s2 = (c + 2) % 3;
    if (c + 2 < 16) {
#pragma unroll
      for (int kcl = 0; kcl < 2; ++kcl) {
        ld8sc(AH[s2][kcl], arh + (c + 2) * 64 + kcl * 32 + kg * 8);
        ld8sc(AL[s2][kcl], arl + (c + 2) * 64 + kcl * 32 + kg * 8);
      }
      ldlo(LOQ[s2], lo_src(glo, jt, c + 2, tid));
    }
    compute_chunk(acc, lds, c, c & 1, lane, AH[s0], AL[s0]);
    if (c < 15) {
      waitv(c + 2 < 16 ? 5 : 0);  // chunk c+1's loads complete
      stlo(lds, (c + 1) & 1, tid, LOQ[s1]);
      block_sync_lds();
    }
  }
}

// encoder L0 extra: x(fp32, K=64, read-only -> cached) x Wih0
__device__ __forceinline__ void gemm_x(f32x4* acc, const float* __restrict__ x, int t,
                                       const unsigned short* __restrict__ wxl, int jt,
                                       const unsigned short* lds) {
  const int tid = threadIdx.x;
  const int lane = tid & 63, wid = tid >> 6;
  const int kg = lane >> 4;
  const int arow = wid * 16 + (lane & 15);
  const float* xr = x + (size_t)arow * (TT * INF) + t * INF;
#pragma unroll
  for (int kc2 = 0; kc2 < 2; ++kc2) {
    const int kb = kc2 * 32 + kg * 8;
    sh8 xh, xl;
#pragma unroll
    for (int e = 0; e < 8; ++e) {
      const float v = xr[kb + e];
      const unsigned short h = f2bf(v);
      xh[e] = (short)h;
      xl[e] = (short)f2bf(v - bf2f(h));
    }
#pragma unroll
    for (int g = 0; g < 4; ++g) {
      const sh8 bH = ld8(lds + SWX_B / 2 + (g * 2 + kc2) * 512 + lane * 8);
      const sh8 bL = ld8(wxl + (((size_t)(g * 64 + jt) * 2 + kc2) * 64 + lane) * 8);
      acc[g] = mfma_bf16(xh, bH, acc[g]);
      acc[g] = mfma_bf16(xl, bH, acc[g]);
      acc[g] = mfma_bf16(xh, bL, acc[g]);
    }
  }
}

__device__ __forceinline__ void store_z(f32x4* acc, float* zb, int jt) {
  const int tid = threadIdx.x;
  const int lane = tid & 63, wid = tid >> 6;
  const int col = lane & 15, kg = lane >> 4;
#pragma unroll
  for (int g = 0; g < 4; ++g) {
    const int row = g * HH + jt * 16 + col;
    const int bq = wid * 16 + kg * 4;
    stx4sc(zb + (size_t)row * BB + bq, acc[g]);
  }
}
__device__ __forceinline__ void add_z(f32x4* acc, const float* zb, int jt) {
  const int tid = threadIdx.x;
  const int lane = tid & 63, wid = tid >> 6;
  const int col = lane & 15, kg = lane >> 4;
  f32x4 t0, t1, t2, t3;
  const int bq = wid * 16 + kg * 4;
  ldx4sc(t0, zb + (size_t)(0 * HH + jt * 16 + col) * BB + bq);
  ldx4sc(t1, zb + (size_t)(1 * HH + jt * 16 + col) * BB + bq);
  ldx4sc(t2, zb + (size_t)(2 * HH + jt * 16 + col) * BB + bq);
  ldx4sc(t3, zb + (size_t)(3 * HH + jt * 16 + col) * BB + bq);
  asm volatile("s_waitcnt vmcnt(0)" ::: "memory");
  __builtin_amdgcn_sched_barrier(0);
  acc[0] += t0;
  acc[1] += t1;
  acc[2] += t2;
  acc[3] += t3;
}

// MODE: 0 plain, 1 rank-1 decoder input, 2 FC partial output
template <int MODE>
__device__ __forceinline__ void cellfin(f32x4* acc, float* creg,
                                        const float* __restrict__ bias, int jt,
                                        unsigned short* __restrict__ nhh,
                                        unsigned short* __restrict__ nhl,
                                        const float* w0g, const float* inp_vec, float fcwj,
                                        float* fc_out) {
  const int tid = threadIdx.x;
  const int lane = tid & 63, wid = tid >> 6;
  const int col = lane & 15, kg = lane >> 4;
  const int j = jt * 16 + col;
  const float b0 = bias[j], b1 = bias[HH + j], b2 = bias[2 * HH + j], b3 = bias[3 * HH + j];
#pragma unroll
  for (int r = 0; r < 4; ++r) {
    const int b = wid * 16 + kg * 4 + r;
    float zi = acc[0][r] + b0;
    float zf = acc[1][r] + b1;
    float zg = acc[2][r] + b2;
    float zo = acc[3][r] + b3;
    if constexpr (MODE == 1) {
      const float ip = inp_vec
          ? __hip_atomic_load(inp_vec + b, __ATOMIC_RELAXED, __HIP_MEMORY_SCOPE_AGENT)
          : 0.f;
      zi += ip * w0g[0];
      zf += ip * w0g[1];
      zg += ip * w0g[2];
      zo += ip * w0g[3];
    }
    const float cn = sigm(zf) * creg[r] + sigm(zi) * tanh_f(zg);
    const float hn = sigm(zo) * tanh_f(cn);
    creg[r] = cn;
    const unsigned short hb = f2bf(hn);
    st16sc(nhh + (size_t)b * HH + j, hb);
    st16sc(nhl + (size_t)b * HH + j, f2bf(hn - bf2f(hb)));
    if constexpr (MODE == 2) {
      float cb = hn * fcwj;
      cb += __shfl_xor(cb, 1);
      cb += __shfl_xor(cb, 2);
      cb += __shfl_xor(cb, 4);
      cb += __shfl_xor(cb, 8);
      if (col == 0) atomicAdd(fc_out + b, cb);
    }
  }
}

__device__ __forceinline__ void zacc(f32x4* acc) {
#pragma unroll
  for (int g = 0; g < 4; ++g) acc[g] = f32x4{0.f, 0.f, 0.f, 0.f};
}

__global__ __launch_bounds__(NTHR, 2) void seq2seq_coop(KArgs a) {
  extern __shared__ unsigned short lds[];
  const int bid = blockIdx.x;
  const int role = bid >> 6;
  const int jt = bid & 63;
  const int tid = threadIdx.x;
  int bseq = 0;

  unsigned short* h0h[2] = {a.h0h0, a.h0h1};
  unsigned short* h0l[2] = {a.h0l0, a.h0l1};
  unsigned short* h1h[2] = {a.h1h0, a.h1h1};
  unsigned short* h1l[2] = {a.h1l0, a.h1l1};
  float* zb[2] = {a.zb0, a.zb1};

  if (role == 0) {
    load_whi(lds, a.whh0e_h, jt);
    load_wx(lds, a.wih0_h, jt);
  } else if (role == 1) {
    load_whi(lds, a.wih1e_h, jt);
  } else {
    load_whi(lds, a.whh1e_h, jt);
  }
  __syncthreads();

  float creg[4] = {};

  // ---- encoder: software-pipelined roles, 1 grid barrier per iteration ----
  for (int i = 0; i < TT + 2; ++i) {
    if (role == 0) {
      if (i < TT) {
        f32x4 acc[4];
        zacc(acc);
        gemm1024(acc, h0h[(i + 1) & 1], h0l[(i + 1) & 1], a.whh0e_l, jt, lds);
        gemm_x(acc, a.x, i, a.wih0_l, jt, lds);
        cellfin<0>(acc, creg, a.bias0e, jt, h0h[i & 1], h0l[i & 1], nullptr, nullptr, 0.f,
                   nullptr);
      }
    } else if (role == 1) {
      if (i >= 1 && i <= TT) {
        const int s = i - 1;
        f32x4 acc[4];
        zacc(acc);
        gemm1024(acc, h0h[s & 1], h0l[s & 1], a.wih1e_l, jt, lds);
        store_z(acc, zb[s & 1], jt);
      }
    } else {
      if (i >= 2) {
        const int s = i - 2;
        f32x4 acc[4];
        zacc(acc);
        gemm1024(acc, h1h[(s + 1) & 1], h1l[(s + 1) & 1], a.whh1e_l, jt, lds);
        add_z(acc, zb[s & 1], jt);
        cellfin<0>(acc, creg, a.bias1e, jt, h1h[s & 1], h1l[s & 1], nullptr, nullptr, 0.f,
                   nullptr);
      }
    }
    gbar(a.arrive, a.go, ++bseq, bid);
  }

  // ---- decoder: reload LDS weights ----
  if (role == 0) load_whi(lds, a.whh0d_h, jt);
  else if (role == 1) load_whi(lds, a.wih1d_h, jt);
  else load_whi(lds, a.whh1d_h, jt);
  __syncthreads();

  float w0g[4] = {0.f, 0.f, 0.f, 0.f};
  float fcwj = 0.f;
  if (role == 0) {
    const int j = jt * 16 + (tid & 15);
    w0g[0] = a.w0col[j];
    w0g[1] = a.w0col[HH + j];
    w0g[2] = a.w0col[2 * HH + j];
    w0g[3] = a.w0col[3 * HH + j];
  }
  if (role == 2) fcwj = a.fcw[jt * 16 + (tid & 15)];

  for (int s = 0; s < SS; ++s) {
    f32x4 acc2[4];
    if (role == 2) {
      zacc(acc2);
      gemm1024(acc2, h1h[(s + 1) & 1], h1l[(s + 1) & 1], a.whh1d_l, jt, lds);
    }
    if (role == 0) {
      f32x4 acc[4];
      zacc(acc);
      gemm1024(acc, h0h[(s + 1) & 1], h0l[(s + 1) & 1], a.whh0d_l, jt, lds);
      cellfin<1>(acc, creg, a.bias0d, jt, h0h[s & 1], h0l[s & 1], w0g,
                 s ? a.out_tmp + (s - 1) * BB : nullptr, 0.f, nullptr);
    }
    gbar(a.arrive, a.go, ++bseq, bid);
    if (role == 1) {
      f32x4 acc[4];
      zacc(acc);
      gemm1024(acc, h0h[s & 1], h0l[s & 1], a.wih1d_l, jt, lds);
      store_z(acc, zb[0], jt);
    }
    gbar(a.arrive, a.go, ++bseq, bid);
    if (role == 2) {
      add_z(acc2, zb[0], jt);
      cellfin<2>(acc2, creg, a.bias1d, jt, h1h[s & 1], h1l[s & 1], nullptr, nullptr, fcwj,
                 a.out_tmp + s * BB);
    }
    gbar(a.arrive, a.go, ++bseq, bid);
  }

  // ---- final: out_tmp (S,B) -> d_out (B,S) ----
  if (bid < 16) {
    const int gi = bid * NTHR + tid;  // gi = b*64 + s
    const int b = gi >> 6, s2 = gi & 63;
    a.outp[gi] =
        __hip_atomic_load(a.out_tmp + s2 * BB + b, __ATOMIC_RELAXED, __HIP_MEMORY_SCOPE_AGENT);
  }
}

extern "C" void kernel_launch(void* const* d_in, const int* in_sizes, int n_in,
                              void* d_out, int out_size, void* d_ws, size_t ws_size,
                              hipStream_t stream) {
  (void)in_sizes; (void)n_in; (void)out_size; (void)ws_size;
  const float* x     = (const float*)d_in[0];
  const float* eWih0 = (const float*)d_in[1];
  const float* eWhh0 = (const float*)d_in[2];
  const float* eBih0 = (const float*)d_in[3];
  const float* eBhh0 = (const float*)d_in[4];
  const float* eWih1 = (const float*)d_in[5];
  const float* eWhh1 = (const float*)d_in[6];
  const float* eBih1 = (const float*)d_in[7];
  const float* eBhh1 = (const float*)d_in[8];
  const float* dWih0 = (const float*)d_in[9];
  const float* dWhh0 = (const float*)d_in[10];
  const float* dBih0 = (const float*)d_in[11];
  const float* dBhh0 = (const float*)d_in[12];
  const float* dWih1 = (const float*)d_in[13];
  const float* dWhh1 = (const float*)d_in[14];
  const float* dBih1 = (const float*)d_in[15];
  const float* dBhh1 = (const float*)d_in[16];
  const float* fcW   = (const float*)d_in[17];
  const float* fcB   = (const float*)d_in[18];
  float* out = (float*)d_out;

  char* base = (char*)d_ws;
  size_t off = 0;
  auto alloc = [&](size_t bytes) -> void* {
    void* p = base + off;
    off = (off + bytes + 255) & ~(size_t)255;
    return p;
  };

  // zero-initialized block (one memset): h buffers + barrier flags
  unsigned short* h0h0 = (unsigned short*)alloc(BB * HH * 2);
  unsigned short* h0h1 = (unsigned short*)alloc(BB * HH * 2);
  unsigned short* h0l0 = (unsigned short*)alloc(BB * HH * 2);
  unsigned short* h0l1 = (unsigned short*)alloc(BB * HH * 2);
  unsigned short* h1h0 = (unsigned short*)alloc(BB * HH * 2);
  unsigned short* h1h1 = (unsigned short*)alloc(BB * HH * 2);
  unsigned short* h1l0 = (unsigned short*)alloc(BB * HH * 2);
  unsigned short* h1l1 = (unsigned short*)alloc(BB * HH * 2);
  int* bar = (int*)alloc((NBLK * 16 + 16) * sizeof(int));
  const size_t zbytes = off;

  float* zb0 = (float*)alloc((size_t)NG * BB * 4);
  float* zb1 = (float*)alloc((size_t)NG * BB * 4);
  float* out_tmp = (float*)alloc(SS * BB * 4);

  unsigned short* wih0_h = (unsigned short*)alloc((size_t)NG * INF * 2);
  unsigned short* wih0_l = (unsigned short*)alloc((size_t)NG * INF * 2);
  auto big = [&]() { return (unsigned short*)alloc((size_t)NG * HH * 2); };
  unsigned short *whh0e_h = big(), *whh0e_l = big();
  unsigned short *wih1e_h = big(), *wih1e_l = big();
  unsigned short *whh1e_h = big(), *whh1e_l = big();
  unsigned short *whh0d_h = big(), *whh0d_l = big();
  unsigned short *wih1d_h = big(), *wih1d_l = big();
  unsigned short *whh1d_h = big(), *whh1d_l = big();
  float* bias0e = (float*)alloc(NG * 4);
  float* bias1e = (float*)alloc(NG * 4);
  float* bias0d = (float*)alloc(NG * 4);
  float* bias1d = (float*)alloc(NG * 4);

  (void)hipMemsetAsync(base, 0, zbytes, stream);
  const int gb = (NG * HH + 255) / 256;
  prep_weight<<<gb, 256, 0, stream>>>(eWhh0, whh0e_h, whh0e_l, 10);
  prep_weight<<<gb, 256, 0, stream>>>(eWih1, wih1e_h, wih1e_l, 10);
  prep_weight<<<gb, 256, 0, stream>>>(eWhh1, whh1e_h, whh1e_l, 10);
  prep_weight<<<gb, 256, 0, stream>>>(dWhh0, whh0d_h, whh0d_l, 10);
  prep_weight<<<gb, 256, 0, stream>>>(dWih1, wih1d_h, wih1d_l, 10);
  prep_weight<<<gb, 256, 0, stream>>>(dWhh1, whh1d_h, whh1d_l, 10);
  prep_weight<<<(NG * INF + 255) / 256, 256, 0, stream>>>(eWih0, wih0_h, wih0_l, 6);
  const int gbias = (NG + 255) / 256;
  prep_bias<<<gbias, 256, 0, stream>>>(eBih0, eBhh0, bias0e);
  prep_bias<<<gbias, 256, 0, stream>>>(eBih1, eBhh1, bias1e);
  prep_bias<<<gbias, 256, 0, stream>>>(dBih0, dBhh0, bias0d);
  prep_bias<<<gbias, 256, 0, stream>>>(dBih1, dBhh1, bias1d);
  init_out<<<(SS * BB + 255) / 256, 256, 0, stream>>>(out_tmp, fcB);

  KArgs ka;
  ka.x = x;
  ka.wih0_h = wih0_h; ka.wih0_l = wih0_l;
  ka.whh0e_h = whh0e_h; ka.whh0e_l = whh0e_l;
  ka.wih1e_h = wih1e_h; ka.wih1e_l = wih1e_l;
  ka.whh1e_h = whh1e_h; ka.whh1e_l = whh1e_l;
  ka.whh0d_h = whh0d_h; ka.whh0d_l = whh0d_l;
  ka.wih1d_h = wih1d_h; ka.wih1d_l = wih1d_l;
  ka.whh1d_h = whh1d_h; ka.whh1d_l = whh1d_l;
  ka.bias0e = bias0e; ka.bias1e = bias1e; ka.bias0d = bias0d; ka.bias1d = bias1d;
  ka.w0col = dWih0; ka.fcw = fcW; ka.fcb = fcB;
  ka.h0h0 = h0h0; ka.h0h1 = h0h1; ka.h0l0 = h0l0; ka.h0l1 = h0l1;
  ka.h1h0 = h1h0; ka.h1h1 = h1h1; ka.h1l0 = h1l0; ka.h1l1 = h1l1;
  ka.zb0 = zb0; ka.zb1 = zb1;
  ka.out_tmp = out_tmp;
  ka.outp = out;
  ka.arrive = bar;
  ka.go = bar + NBLK * 16;

  (void)hipFuncSetAttribute((const void*)seq2seq_coop,
                            hipFuncAttributeMaxDynamicSharedMemorySize, LDS_BYTES);
  seq2seq_coop<<<dim3(NBLK), dim3(NTHR), LDS_BYTES, stream>>>(ka);
}